// Round 7
// baseline (960.311 us; speedup 1.0000x reference)
//
#include <hip/hip_runtime.h>
#include <math.h>

constexpr float LEAKY = 0.2f;

__device__ __forceinline__ float4 ldf4(const float* p){ return *reinterpret_cast<const float4*>(p); }
__device__ __forceinline__ void stf4(float* p, float4 v){ *reinterpret_cast<float4*>(p) = v; }
__device__ __forceinline__ float dot4(float4 a, float4 b){ return a.x*b.x + a.y*b.y + a.z*b.z + a.w*b.w; }
__device__ __forceinline__ float4 fma4(float s, float4 b, float4 acc){
    acc.x += s*b.x; acc.y += s*b.y; acc.z += s*b.z; acc.w += s*b.w; return acc;
}
__device__ __forceinline__ float lrelu(float f){ return f > 0.f ? f : LEAKY*f; }
__device__ __forceinline__ float4 lrelu4(float s, float4 t){
    float4 r; r.x = lrelu(s+t.x); r.y = lrelu(s+t.y); r.z = lrelu(s+t.z); r.w = lrelu(s+t.w); return r;
}
__device__ __forceinline__ float vmax4(float4 v){ return fmaxf(fmaxf(v.x,v.y), fmaxf(v.z,v.w)); }
__device__ __forceinline__ float vsum4(float4 v){ return v.x+v.y+v.z+v.w; }
__device__ __forceinline__ float4 exp4(float4 a, float mx){
    float4 r; r.x = __expf(a.x-mx); r.y = __expf(a.y-mx); r.z = __expf(a.z-mx); r.w = __expf(a.w-mx); return r;
}

// ws layout (floats): wv[12*64]@0 | WspT0[12*64]@768 | WspT1[5*64]@1536 | WtpT0[32*64]@1856 | WtpT1[16*64]@3904
__global__ void prep_kernel(const float* __restrict__ W,
    const float* a0, const float* a1, const float* a2,  const float* a3,
    const float* a4, const float* a5, const float* a6,  const float* a7,
    const float* a8, const float* a9, const float* a10, const float* a11,
    const float* __restrict__ Wsp0, const float* __restrict__ Wsp1,
    const float* __restrict__ Wtp0, const float* __restrict__ Wtp1,
    float* __restrict__ ws)
{
    int blk = blockIdx.x, t = threadIdx.x;
    if (blk < 12) {
        const float* as[12] = {a0,a1,a2,a3,a4,a5,a6,a7,a8,a9,a10,a11};
        const float* a = as[blk];
        float s = 0.f;
        #pragma unroll
        for (int h = 0; h < 128; ++h) s += W[t*128 + h] * a[h];
        ws[blk*64 + t] = s;
    } else if (blk == 12) {
        for (int i = t; i < 768; i += 64) { int k = i >> 6, c = i & 63; ws[768 + i] = Wsp0[c*12 + k]; }
    } else if (blk == 13) {
        for (int i = t; i < 320; i += 64) { int k = i >> 6, c = i & 63; ws[1536 + i] = Wsp1[c*5 + k]; }
    } else if (blk == 14) {
        for (int i = t; i < 2048; i += 64) { int k = i >> 6, c = i & 63; ws[1856 + i] = Wtp0[c*32 + k]; }
    } else {
        for (int i = t; i < 1024; i += 64) { int k = i >> 6, c = i & 63; ws[3904 + i] = Wtp1[c*16 + k]; }
    }
}

// ================== TEMPORAL: 6400 graphs of 64 nodes, 256 threads ==================
// LDS = 13312 floats = 53248 B exactly -> 3 blocks/CU (159744 <= 163840).
// (256,4): VGPR cap 128 (safe: max live ~80) -> >=3 blocks resident.
// GEMM phases use 8x4 tiles on 1-2 waves: LDS-pipe-bound regime, idle threads are free.
__global__ __launch_bounds__(256, 4)
void temporal_kernel(const float* __restrict__ src, const float* __restrict__ wvg,
                     const float* __restrict__ WpT0, const float* __restrict__ WpT1,
                     const float* __restrict__ b0, const float* __restrict__ b1,
                     float* __restrict__ out, int nwg8)
{
    __shared__ __align__(16) float Rx0[4352];   // x0[64][68]; tenants after deps clear
    __shared__ __align__(16) float RA0[4352];   // A0 [64][68]
    __shared__ __align__(16) float RPR[2304];   // P0T[32][68] -> x1[32][68] -> M1[64][36] -> M2[64][20]
    __shared__ __align__(16) float RS0[2304];   // S0[64][36]

    float* x0  = Rx0;
    float* A1  = Rx0;          // [32][36] 0..1152      (P6 -> dead after G1b)
    float* A1T = Rx0 + 1152;   // [32][36] ..2304       (P6 -> dead after G1)
    float* P1T = Rx0 + 2304;   // [16][36] ..2880       (P6 -> dead after G1b)
    float* S1  = Rx0 + 2880;   // [32][20] ..3520       (G1b -> dead after G2b)
    float* S1T = Rx0 + 3520;   // [16][36] ..4096       (G2b -> dead after G3)
    float* uav = Rx0 + 4096;   // [64]                  (P5 -> G3b; x0 dead after P4)
    float* vav = Rx0 + 4160;   // [64]
    float* rxa = Rx0 + 4224;   // [16]                  (G3b -> G4)
    float* rsa = Rx0 + 4240;   // [16]
    float* A2T = Rx0 + 2304;   // [16][20]              (G4, after P1T dead)
    float* S01 = Rx0;          // [64][20]              (G3, after A1/A1T dead)
    float* A0  = RA0;
    float* P0T = RPR;          // [32][68]
    float* x1  = RPR;          // (P0T dead after P2)
    float* M1  = RPR;          // [64][36] (x1 dead after P6)
    float* M2  = RPR;          // [64][20] (M1 dead after G2)
    float* sv  = RPR + 2176;   // [64]  coexists with P0T/x1 (<2176); dead before M1 write
    float* tv  = RPR + 2240;   // [64]
    float* S0  = RS0;          // [64][36]

    const int t = threadIdx.x;
    const int g = (blockIdx.x & 7) * nwg8 + (blockIdx.x >> 3);
    const int b = g / 25, inner = g - b*25;
    const float* srcb = src + (size_t)b*102400 + inner;  // + c*1600 + r*25 (inner = joint, stride 1)

    float facc[8][4];   // fusion accumulator, threads 0..127, lives G2..G6

    // ---- L: load x0[r][c] ----
    for (int i = t; i < 1024; i += 256) {
        int r = i & 63, c0 = (i >> 6) << 2;
        float4 v;
        v.x = srcb[(c0+0)*1600 + r*25];
        v.y = srcb[(c0+1)*1600 + r*25];
        v.z = srcb[(c0+2)*1600 + r*25];
        v.w = srcb[(c0+3)*1600 + r*25];
        stf4(&x0[r*68 + c0], v);
    }
    __syncthreads();

    // ---- DP0: s0/t0 dots (t<64, both dots share x-row read) || P0T 4k x 4m (t 64..191) ----
    if (t < 64) {
        float s = 0.f, tt = 0.f;
        #pragma unroll
        for (int c4 = 0; c4 < 16; ++c4) {
            float4 xv = ldf4(&x0[t*68 + 4*c4]);
            s  += dot4(xv, ldf4(&wvg[4*c4]));
            tt += dot4(xv, ldf4(&wvg[64 + 4*c4]));
        }
        sv[t] = s; tv[t] = tt;
    } else if (t < 192) {
        int tp = t - 64, k0 = tp & 7, m0 = tp >> 3;
        float acc[4][4] = {};
        #pragma unroll
        for (int c4 = 0; c4 < 16; ++c4) {
            float4 w4[4], xm[4];
            #pragma unroll
            for (int i = 0; i < 4; ++i) w4[i] = ldf4(&WpT0[(k0+8*i)*64 + 4*c4]);
            #pragma unroll
            for (int j = 0; j < 4; ++j) xm[j] = ldf4(&x0[(m0+16*j)*68 + 4*c4]);
            #pragma unroll
            for (int i = 0; i < 4; ++i)
                #pragma unroll
                for (int j = 0; j < 4; ++j) acc[i][j] += dot4(w4[i], xm[j]);
        }
        #pragma unroll
        for (int i = 0; i < 4; ++i)
            #pragma unroll
            for (int j = 0; j < 4; ++j) P0T[(k0+8*i)*68 + m0+16*j] = acc[i][j];
    }
    __syncthreads();

    // ---- P1: A0 = lrelu(s + t^T) ----
    for (int i = t; i < 1024; i += 256) {
        int p = i >> 4, q4 = i & 15;
        stf4(&A0[p*68 + 4*q4], lrelu4(sv[p], ldf4(&tv[4*q4])));
    }
    __syncthreads();

    // ---- P2: S0raw = A0 @ P0 + b0, 8p x 4k tiles, 1 wave ----
    if (t < 64) {
        int k0 = t & 7, p0 = t >> 3;
        float acc[8][4];
        #pragma unroll
        for (int i = 0; i < 8; ++i)
            #pragma unroll
            for (int j = 0; j < 4; ++j) acc[i][j] = b0[k0 + 8*j];
        #pragma unroll
        for (int m4 = 0; m4 < 16; ++m4) {
            float4 a[8];
            #pragma unroll
            for (int i = 0; i < 8; ++i) a[i] = ldf4(&A0[(p0+8*i)*68 + 4*m4]);
            #pragma unroll
            for (int j = 0; j < 4; ++j) {
                float4 pk = ldf4(&P0T[(k0+8*j)*68 + 4*m4]);
                #pragma unroll
                for (int i = 0; i < 8; ++i) acc[i][j] += dot4(a[i], pk);
            }
        }
        #pragma unroll
        for (int i = 0; i < 8; ++i)
            #pragma unroll
            for (int j = 0; j < 4; ++j) S0[(p0+8*i)*36 + k0+8*j] = acc[i][j];
    }
    __syncthreads();

    // ---- P3: row softmax S0, 8 lanes/row, 2 rows/thread ----
    {
        int p0 = t >> 3, l = t & 7;
        #pragma unroll
        for (int h = 0; h < 2; ++h) {
            int p = p0 + 32*h;
            float4 v = ldf4(&S0[p*36 + 4*l]);
            float mx = vmax4(v);
            mx = fmaxf(mx, __shfl_xor(mx,1)); mx = fmaxf(mx, __shfl_xor(mx,2)); mx = fmaxf(mx, __shfl_xor(mx,4));
            v = exp4(v, mx);
            float sm = vsum4(v);
            sm += __shfl_xor(sm,1); sm += __shfl_xor(sm,2); sm += __shfl_xor(sm,4);
            float inv = 1.f/sm;
            v.x *= inv; v.y *= inv; v.z *= inv; v.w *= inv;
            stf4(&S0[p*36 + 4*l], v);
        }
    }
    __syncthreads();

    // ---- P4: x1 = S0^T @ x0, outer-product 4k x 8c, 1 wave ----
    if (t < 64) {
        int k0 = t >> 3, c0 = (t & 7) << 3;
        float4 accA[4] = {}, accB[4] = {};
        #pragma unroll 8
        for (int p = 0; p < 64; ++p) {
            float4 xa = ldf4(&x0[p*68 + c0]);
            float4 xb = ldf4(&x0[p*68 + c0 + 4]);
            #pragma unroll
            for (int i = 0; i < 4; ++i) {
                float s = S0[p*36 + k0 + 8*i];
                accA[i] = fma4(s, xa, accA[i]);
                accB[i] = fma4(s, xb, accB[i]);
            }
        }
        #pragma unroll
        for (int i = 0; i < 4; ++i) {
            stf4(&x1[(k0+8*i)*68 + c0], accA[i]);
            stf4(&x1[(k0+8*i)*68 + c0 + 4], accB[i]);
        }
    }
    __syncthreads();

    // ---- P5: s1/t1 | u/v dots (x1 row shared per pair), 1 wave ----
    if (t < 64) {
        int p = t & 31, pair = t >> 5;
        const float* wa = wvg + (2 + 2*pair)*64;
        const float* wb = wvg + (3 + 2*pair)*64;
        float a = 0.f, c2 = 0.f;
        #pragma unroll
        for (int c4 = 0; c4 < 16; ++c4) {
            float4 xv = ldf4(&x1[p*68 + 4*c4]);
            a  += dot4(xv, ldf4(&wa[4*c4]));
            c2 += dot4(xv, ldf4(&wb[4*c4]));
        }
        if (pair == 0) { sv[p] = a; tv[p] = c2; }
        else           { uav[p] = a; vav[p] = c2; }
    }
    __syncthreads();

    // ---- P6: A1+A1T (t<128) || P1T = (x1@Wp1)^T 2j x 8k (t 128..191) ----
    if (t < 128) {
        for (int i = t; i < 512; i += 128) {
            int half = i >> 8, idx = i & 255, p = idx >> 3, q4 = idx & 7;
            if (half == 0) stf4(&A1 [p*36 + 4*q4], lrelu4(sv[p], ldf4(&tv[4*q4])));
            else           stf4(&A1T[p*36 + 4*q4], lrelu4(tv[p], ldf4(&sv[4*q4])));
        }
    } else if (t < 192) {
        int tp = t - 128, j0 = tp >> 3, k0 = tp & 7;
        float acc[2][4] = {};
        #pragma unroll
        for (int c4 = 0; c4 < 16; ++c4) {
            float4 w4[2], xk[4];
            w4[0] = ldf4(&WpT1[j0*64 + 4*c4]);
            w4[1] = ldf4(&WpT1[(j0+8)*64 + 4*c4]);
            #pragma unroll
            for (int jj = 0; jj < 4; ++jj) xk[jj] = ldf4(&x1[(k0+8*jj)*68 + 4*c4]);
            #pragma unroll
            for (int i = 0; i < 2; ++i)
                #pragma unroll
                for (int jj = 0; jj < 4; ++jj) acc[i][jj] += dot4(w4[i], xk[jj]);
        }
        #pragma unroll
        for (int i = 0; i < 2; ++i)
            #pragma unroll
            for (int jj = 0; jj < 4; ++jj) P1T[(j0+8*i)*36 + k0+8*jj] = acc[i][jj];
    }
    __syncthreads();

    // ---- G1: M1 = S0@A1 8p x 4k (t<64) || G1b: S1raw = A1@P1+b1 4m x 2j (t 64..127) ----
    if (t < 64) {
        int k0 = t & 7, p0 = t >> 3;
        float acc[8][4] = {};
        #pragma unroll
        for (int m4 = 0; m4 < 8; ++m4) {
            float4 a[8];
            #pragma unroll
            for (int i = 0; i < 8; ++i) a[i] = ldf4(&S0[(p0+8*i)*36 + 4*m4]);
            #pragma unroll
            for (int j = 0; j < 4; ++j) {
                float4 bv = ldf4(&A1T[(k0+8*j)*36 + 4*m4]);
                #pragma unroll
                for (int i = 0; i < 8; ++i) acc[i][j] += dot4(a[i], bv);
            }
        }
        #pragma unroll
        for (int i = 0; i < 8; ++i)
            #pragma unroll
            for (int j = 0; j < 4; ++j) M1[(p0+8*i)*36 + k0+8*j] = acc[i][j];
    } else if (t < 128) {
        int tp = t - 64, m0 = tp >> 3, j0 = tp & 7;
        float acc[4][2];
        #pragma unroll
        for (int i = 0; i < 4; ++i) { acc[i][0] = b1[j0]; acc[i][1] = b1[j0+8]; }
        #pragma unroll
        for (int k4 = 0; k4 < 8; ++k4) {
            float4 am[4];
            #pragma unroll
            for (int i = 0; i < 4; ++i) am[i] = ldf4(&A1[(m0+8*i)*36 + 4*k4]);
            #pragma unroll
            for (int jj = 0; jj < 2; ++jj) {
                float4 pj = ldf4(&P1T[(j0+8*jj)*36 + 4*k4]);
                #pragma unroll
                for (int i = 0; i < 4; ++i) acc[i][jj] += dot4(am[i], pj);
            }
        }
        #pragma unroll
        for (int i = 0; i < 4; ++i)
            #pragma unroll
            for (int jj = 0; jj < 2; ++jj) S1[(m0+8*i)*20 + j0+8*jj] = acc[i][jj];
    }
    __syncthreads();

    // ---- G2: facc = A0 + M1@S0^T (8p x 4q regs, t<128); then G2b: softmax S1 -> S1T ----
    if (t < 128) {
        int q0 = t & 15, p0 = t >> 4;
        #pragma unroll
        for (int i = 0; i < 8; ++i)
            #pragma unroll
            for (int j = 0; j < 4; ++j) facc[i][j] = A0[(p0+8*i)*68 + q0+16*j];
        #pragma unroll
        for (int m4 = 0; m4 < 8; ++m4) {
            float4 sj[4];
            #pragma unroll
            for (int j = 0; j < 4; ++j) sj[j] = ldf4(&S0[(q0+16*j)*36 + 4*m4]);
            #pragma unroll
            for (int i = 0; i < 8; ++i) {
                float4 mi = ldf4(&M1[(p0+8*i)*36 + 4*m4]);
                #pragma unroll
                for (int j = 0; j < 4; ++j) facc[i][j] += dot4(mi, sj[j]);
            }
        }
        // G2b: softmax S1 rows (4 lanes/row), write transposed
        int m = t >> 2, l = t & 3;
        float4 v = ldf4(&S1[m*20 + 4*l]);
        float mx = vmax4(v);
        mx = fmaxf(mx, __shfl_xor(mx,1)); mx = fmaxf(mx, __shfl_xor(mx,2));
        v = exp4(v, mx);
        float sm = vsum4(v);
        sm += __shfl_xor(sm,1); sm += __shfl_xor(sm,2);
        float inv = 1.f/sm;
        S1T[(4*l+0)*36 + m] = v.x*inv;
        S1T[(4*l+1)*36 + m] = v.y*inv;
        S1T[(4*l+2)*36 + m] = v.z*inv;
        S1T[(4*l+3)*36 + m] = v.w*inv;
    }
    __syncthreads();

    // ---- G3: S01 = S0@S1 8p x 2j (t<64) || G3b: rxa/rsa = S1T . (u,v) (t 64..95) ----
    if (t < 64) {
        int j0 = t & 7, p0 = t >> 3;
        float acc[8][2] = {};
        #pragma unroll
        for (int m4 = 0; m4 < 8; ++m4) {
            float4 a[8];
            #pragma unroll
            for (int i = 0; i < 8; ++i) a[i] = ldf4(&S0[(p0+8*i)*36 + 4*m4]);
            #pragma unroll
            for (int jj = 0; jj < 2; ++jj) {
                float4 bv = ldf4(&S1T[(j0+8*jj)*36 + 4*m4]);
                #pragma unroll
                for (int i = 0; i < 8; ++i) acc[i][jj] += dot4(a[i], bv);
            }
        }
        #pragma unroll
        for (int i = 0; i < 8; ++i)
            #pragma unroll
            for (int jj = 0; jj < 2; ++jj) S01[(p0+8*i)*20 + j0+8*jj] = acc[i][jj];
    } else if (t < 96) {
        int tp = t - 64, j = tp & 15, which = tp >> 4;
        const float* uv = which ? vav : uav;
        float acc = 0.f;
        #pragma unroll
        for (int m4 = 0; m4 < 8; ++m4)
            acc += dot4(ldf4(&S1T[j*36 + 4*m4]), ldf4(&uv[4*m4]));
        if (which) rsa[j] = acc; else rxa[j] = acc;
    }
    __syncthreads();

    // ---- G4: A2T[q][p] = lrelu(rxa[p] + rsa[q]) ----
    {
        int q = t >> 4, p = t & 15;
        A2T[q*20 + p] = lrelu(rxa[p] + rsa[q]);
    }
    __syncthreads();

    // ---- G5: M2 = S01@A2, 8p x 2k (t<64) ----
    if (t < 64) {
        int k0 = t & 7, p0 = t >> 3;
        float acc[8][2] = {};
        #pragma unroll
        for (int m4 = 0; m4 < 4; ++m4) {
            float4 a[8];
            #pragma unroll
            for (int i = 0; i < 8; ++i) a[i] = ldf4(&S01[(p0+8*i)*20 + 4*m4]);
            #pragma unroll
            for (int jj = 0; jj < 2; ++jj) {
                float4 bv = ldf4(&A2T[(k0+8*jj)*20 + 4*m4]);
                #pragma unroll
                for (int i = 0; i < 8; ++i) acc[i][jj] += dot4(a[i], bv);
            }
        }
        #pragma unroll
        for (int i = 0; i < 8; ++i)
            #pragma unroll
            for (int jj = 0; jj < 2; ++jj) M2[(p0+8*i)*20 + k0+8*jj] = acc[i][jj];
    }
    __syncthreads();

    // ---- G6 (fused): facc += M2@S01^T; row softmax in regs via 16-lane shfl; write out ----
    if (t < 128) {
        int q0 = t & 15, p0 = t >> 4;
        #pragma unroll
        for (int m4 = 0; m4 < 4; ++m4) {
            float4 sj[4];
            #pragma unroll
            for (int j = 0; j < 4; ++j) sj[j] = ldf4(&S01[(q0+16*j)*20 + 4*m4]);
            #pragma unroll
            for (int i = 0; i < 8; ++i) {
                float4 mi = ldf4(&M2[(p0+8*i)*20 + 4*m4]);
                #pragma unroll
                for (int j = 0; j < 4; ++j) facc[i][j] += dot4(mi, sj[j]);
            }
        }
        size_t base = (size_t)g * 4096;
        #pragma unroll
        for (int i = 0; i < 8; ++i) {
            int p = p0 + 8*i;
            float mx = fmaxf(fmaxf(facc[i][0], facc[i][1]), fmaxf(facc[i][2], facc[i][3]));
            mx = fmaxf(mx, __shfl_xor(mx,1)); mx = fmaxf(mx, __shfl_xor(mx,2));
            mx = fmaxf(mx, __shfl_xor(mx,4)); mx = fmaxf(mx, __shfl_xor(mx,8));
            float e0 = __expf(facc[i][0]-mx), e1 = __expf(facc[i][1]-mx),
                  e2 = __expf(facc[i][2]-mx), e3 = __expf(facc[i][3]-mx);
            float sm = e0+e1+e2+e3;
            sm += __shfl_xor(sm,1); sm += __shfl_xor(sm,2); sm += __shfl_xor(sm,4); sm += __shfl_xor(sm,8);
            float inv = 1.f/sm;
            out[base + p*64 + q0]    = e0*inv;
            out[base + p*64 + q0+16] = e1*inv;
            out[base + p*64 + q0+32] = e2*inv;
            out[base + p*64 + q0+48] = e3*inv;
        }
    }
}

// ================== SPATIAL: 16384 graphs of 25 nodes, 256 threads ==================
__global__ __launch_bounds__(256, 4)
void spatial_kernel(const float* __restrict__ src, const float* __restrict__ wvg,
                    const float* __restrict__ WpT0, const float* __restrict__ WpT1,
                    const float* __restrict__ b0, const float* __restrict__ b1,
                    float* __restrict__ out, int nwg8)
{
    __shared__ __align__(16) float Rx0[1700];   // x0[25][68]; then tenants
    __shared__ __align__(16) float RA0[700];    // A0/fusion [25][28]
    __shared__ __align__(16) float RPR[816];    // P0T[12][28] -> x1[12][68] -> M1[25][20] -> M2[25][12]
    __shared__ __align__(16) float RS0[500];    // S0[25][20]
    __shared__ __align__(16) float sv[32], tv[32], ua[32], va[32], rxa[8], rsa[8];

    float* x0  = Rx0;
    float* A1  = Rx0;          // [12][20]
    float* A1T = Rx0 + 240;    // [12][20]
    float* P1T = Rx0 + 480;    // [5][12]
    float* S1  = Rx0 + 540;    // [12][12]
    float* S1T = Rx0 + 684;    // [5][12]
    float* A2T = Rx0 + 744;    // [5][12]
    float* S01 = Rx0 + 804;    // [25][12]
    float* A0  = RA0;
    float* P0T = RPR;          // [12][28]
    float* x1  = RPR;          // [12][68]
    float* M1  = RPR;          // [25][20]
    float* M2  = RPR;          // [25][12]
    float* S0  = RS0;          // [25][20]

    const int t = threadIdx.x;
    const int g = (blockIdx.x & 7) * nwg8 + (blockIdx.x >> 3);
    const int b = g >> 6, inner = g & 63;
    const float* srcb = src + (size_t)b*102400 + inner*25;  // + c*1600 + r  (inner = timestep, stride 25)

    // ---- L ----
    for (int i = t; i < 400; i += 256) {
        int r = i % 25, c0 = (i / 25) << 2;
        float4 v;
        v.x = srcb[(c0+0)*1600 + r];
        v.y = srcb[(c0+1)*1600 + r];
        v.z = srcb[(c0+2)*1600 + r];
        v.w = srcb[(c0+3)*1600 + r];
        stf4(&x0[r*68 + c0], v);
    }
    __syncthreads();

    // ---- P0: dots || P0T (zero-padded cols 25..27) ----
    if (t < 50) {
        int which = t / 25, p = t - which*25;
        const float* w = wvg + which*64;
        float a = 0.f;
        #pragma unroll
        for (int c4 = 0; c4 < 16; ++c4) a += dot4(ldf4(&x0[p*68 + 4*c4]), ldf4(&w[4*c4]));
        if (which) tv[p] = a; else sv[p] = a;
    }
    for (int i = t; i < 336; i += 256) {
        int k = i / 28, m = i - k*28;
        float a = 0.f;
        if (m < 25) {
            #pragma unroll
            for (int c4 = 0; c4 < 16; ++c4) a += dot4(ldf4(&WpT0[k*64 + 4*c4]), ldf4(&x0[m*68 + 4*c4]));
        }
        P0T[k*28 + m] = a;
    }
    __syncthreads();

    // ---- P1: A0 (pads = -1e30) ----
    for (int i = t; i < 700; i += 256) {
        int p = i / 28, q = i - p*28;
        A0[i] = (q < 25) ? lrelu(sv[p] + tv[q]) : -1e30f;
    }
    __syncthreads();

    // ---- P2: S0raw ----
    for (int i = t; i < 300; i += 256) {
        int p = i / 12, k = i - p*12;
        float acc = b0[k];
        #pragma unroll
        for (int m4 = 0; m4 < 7; ++m4) acc += dot4(ldf4(&A0[p*28 + 4*m4]), ldf4(&P0T[k*28 + 4*m4]));
        S0[p*20 + k] = acc;
    }
    __syncthreads();

    // ---- P3: softmax S0 rows ----
    if (t < 25) {
        float4 r[3]; float mx = -1e30f;
        #pragma unroll
        for (int u = 0; u < 3; ++u) { r[u] = ldf4(&S0[t*20 + 4*u]); mx = fmaxf(mx, vmax4(r[u])); }
        float sm = 0.f;
        #pragma unroll
        for (int u = 0; u < 3; ++u) { r[u] = exp4(r[u], mx); sm += vsum4(r[u]); }
        float inv = 1.f/sm;
        #pragma unroll
        for (int u = 0; u < 3; ++u) {
            r[u].x *= inv; r[u].y *= inv; r[u].z *= inv; r[u].w *= inv;
            stf4(&S0[t*20 + 4*u], r[u]);
        }
    }
    __syncthreads();

    // ---- P4: x1[k][c] ----
    if (t < 96) {
        int k = t >> 3, c0 = (t & 7) << 3;
        float4 a = {0,0,0,0}, bb = {0,0,0,0};
        #pragma unroll
        for (int p = 0; p < 25; ++p) {
            float s = S0[p*20 + k];
            a  = fma4(s, ldf4(&x0[p*68 + c0]), a);
            bb = fma4(s, ldf4(&x0[p*68 + c0 + 4]), bb);
        }
        stf4(&x1[k*68 + c0], a);
        stf4(&x1[k*68 + c0 + 4], bb);
    }
    __syncthreads();

    // ---- P5: dots || P1T ----
    if (t < 48) {
        int which = t / 12, p = t - which*12;
        const float* w = wvg + (2+which)*64;
        float a = 0.f;
        #pragma unroll
        for (int c4 = 0; c4 < 16; ++c4) a += dot4(ldf4(&x1[p*68 + 4*c4]), ldf4(&w[4*c4]));
        if (which == 0) sv[p] = a; else if (which == 1) tv[p] = a;
        else if (which == 2) ua[p] = a; else va[p] = a;
    }
    for (int i = t; i < 60; i += 256) {
        int j = i / 12, k = i - j*12;
        float a = 0.f;
        #pragma unroll
        for (int c4 = 0; c4 < 16; ++c4) a += dot4(ldf4(&WpT1[j*64 + 4*c4]), ldf4(&x1[k*68 + 4*c4]));
        P1T[j*12 + k] = a;
    }
    __syncthreads();

    // ---- P6: A1, A1T ----
    for (int i = t; i < 288; i += 256) {
        int mat = i / 144, rr = (i - mat*144) / 12, q = i % 12;
        if (mat == 0) A1 [rr*20 + q] = lrelu(sv[rr] + tv[q]);
        else          A1T[rr*20 + q] = lrelu(sv[q] + tv[rr]);
    }
    __syncthreads();

    // ---- G1: M1 || S1raw ----
    for (int i = t; i < 300; i += 256) {
        int p = i / 12, k = i - p*12;
        float acc = 0.f;
        #pragma unroll
        for (int m4 = 0; m4 < 3; ++m4) acc += dot4(ldf4(&S0[p*20 + 4*m4]), ldf4(&A1T[k*20 + 4*m4]));
        M1[p*20 + k] = acc;
    }
    for (int i = t; i < 60; i += 256) {
        int m = i / 5, j = i - m*5;
        float acc = b1[j];
        #pragma unroll
        for (int k4 = 0; k4 < 3; ++k4) acc += dot4(ldf4(&A1[m*20 + 4*k4]), ldf4(&P1T[j*12 + 4*k4]));
        S1[m*12 + j] = acc;
    }
    __syncthreads();

    // ---- G2a: softmax S1 || fusion pass1 ----
    if (t < 12) {
        float mx = -1e30f;
        float r0 = S1[t*12+0], r1 = S1[t*12+1], r2 = S1[t*12+2], r3 = S1[t*12+3], r4 = S1[t*12+4];
        mx = fmaxf(fmaxf(fmaxf(r0,r1), fmaxf(r2,r3)), r4);
        r0 = __expf(r0-mx); r1 = __expf(r1-mx); r2 = __expf(r2-mx); r3 = __expf(r3-mx); r4 = __expf(r4-mx);
        float inv = 1.f/(r0+r1+r2+r3+r4);
        S1[t*12+0] = r0*inv; S1[t*12+1] = r1*inv; S1[t*12+2] = r2*inv; S1[t*12+3] = r3*inv; S1[t*12+4] = r4*inv;
    }
    for (int i = t; i < 625; i += 256) {
        int p = i / 25, q = i - p*25;
        float acc = A0[p*28 + q];
        #pragma unroll
        for (int m4 = 0; m4 < 3; ++m4) acc += dot4(ldf4(&M1[p*20 + 4*m4]), ldf4(&S0[q*20 + 4*m4]));
        A0[p*28 + q] = acc;
    }
    __syncthreads();

    // ---- G2b: S1T || rxa/rsa ----
    for (int i = t; i < 60; i += 256) {
        int j = i / 12, m = i - j*12;
        S1T[j*12 + m] = S1[m*12 + j];
    }
    if (t >= 64 && t < 74) {
        int tp = t - 64, which = tp / 5, k = tp - which*5;
        float a = 0.f;
        #pragma unroll
        for (int n = 0; n < 12; ++n) a += S1[n*12 + k] * (which ? va[n] : ua[n]);
        if (which) rsa[k] = a; else rxa[k] = a;
    }
    __syncthreads();

    // ---- G3: A2T (zero-padded) || S01 (zero-padded) ----
    for (int i = t; i < 40; i += 256) {
        int q = i >> 3, p = i & 7;
        A2T[q*12 + p] = (p < 5) ? lrelu(rxa[p] + rsa[q]) : 0.f;
    }
    for (int i = t; i < 200; i += 256) {
        int p = i >> 3, c = i & 7;
        float acc = 0.f;
        if (c < 5) {
            #pragma unroll
            for (int m4 = 0; m4 < 3; ++m4) acc += dot4(ldf4(&S0[p*20 + 4*m4]), ldf4(&S1T[c*12 + 4*m4]));
        }
        S01[p*12 + c] = acc;
    }
    __syncthreads();

    // ---- G4: M2 (zero-padded) ----
    for (int i = t; i < 200; i += 256) {
        int p = i >> 3, k = i & 7;
        float acc = 0.f;
        if (k < 5) {
            #pragma unroll
            for (int m4 = 0; m4 < 2; ++m4) acc += dot4(ldf4(&S01[p*12 + 4*m4]), ldf4(&A2T[k*12 + 4*m4]));
        }
        M2[p*12 + k] = acc;
    }
    __syncthreads();

    // ---- G5: fusion pass2 ----
    for (int i = t; i < 625; i += 256) {
        int p = i / 25, q = i - p*25;
        float acc = A0[p*28 + q];
        #pragma unroll
        for (int m4 = 0; m4 < 2; ++m4) acc += dot4(ldf4(&M2[p*12 + 4*m4]), ldf4(&S01[q*12 + 4*m4]));
        A0[p*28 + q] = acc;
    }
    __syncthreads();

    // ---- P13: stats ----
    if (t < 25) {
        float4 r[7]; float mx = -1e30f;
        #pragma unroll
        for (int u = 0; u < 7; ++u) { r[u] = ldf4(&A0[t*28 + 4*u]); mx = fmaxf(mx, vmax4(r[u])); }
        float sm = 0.f;
        #pragma unroll
        for (int u = 0; u < 7; ++u) sm += vsum4(exp4(r[u], mx));
        sv[t] = mx; tv[t] = 1.f/sm;
    }
    __syncthreads();

    // ---- P14 ----
    for (int i = t; i < 625; i += 256) {
        int p = i / 25, q = i - p*25;
        out[(size_t)g*625 + i] = __expf(A0[p*28 + q] - sv[p]) * tv[p];
    }
}

extern "C" void kernel_launch(void* const* d_in, const int* in_sizes, int n_in,
                              void* d_out, int out_size, void* d_ws, size_t ws_size,
                              hipStream_t stream) {
    const float* src = (const float*)d_in[0];
    const float* W   = (const float*)d_in[1];
    float* ws = (float*)d_ws;

    prep_kernel<<<16, 64, 0, stream>>>(W,
        (const float*)d_in[2],  (const float*)d_in[3],    // as_src0, as_dst0
        (const float*)d_in[6],  (const float*)d_in[7],    // as_src1, as_dst1
        (const float*)d_in[10], (const float*)d_in[11],   // as_src2, as_dst2
        (const float*)d_in[4],  (const float*)d_in[5],    // at_src0, at_dst0
        (const float*)d_in[8],  (const float*)d_in[9],    // at_src1, at_dst1
        (const float*)d_in[12], (const float*)d_in[13],   // at_src2, at_dst2
        (const float*)d_in[14], (const float*)d_in[16],   // Wsp0, Wsp1
        (const float*)d_in[18], (const float*)d_in[20],   // Wtp0, Wtp1
        ws);

    float* out = (float*)d_out;
    spatial_kernel<<<16384, 256, 0, stream>>>(
        src, ws, ws + 768, ws + 1536,
        (const float*)d_in[15], (const float*)d_in[17],
        out, 16384/8);
    temporal_kernel<<<6400, 256, 0, stream>>>(
        src, ws + 384, ws + 1856, ws + 3904,
        (const float*)d_in[19], (const float*)d_in[21],
        out + 10240000, 6400/8);
}

// Round 8
// 515.760 us; speedup vs baseline: 1.8619x; 1.8619x over previous
//
#include <hip/hip_runtime.h>
#include <math.h>

constexpr float LEAKY = 0.2f;

__device__ __forceinline__ float4 ldf4(const float* p){ return *reinterpret_cast<const float4*>(p); }
__device__ __forceinline__ void stf4(float* p, float4 v){ *reinterpret_cast<float4*>(p) = v; }
__device__ __forceinline__ float dot4(float4 a, float4 b){ return a.x*b.x + a.y*b.y + a.z*b.z + a.w*b.w; }
__device__ __forceinline__ float4 fma4(float s, float4 b, float4 acc){
    acc.x += s*b.x; acc.y += s*b.y; acc.z += s*b.z; acc.w += s*b.w; return acc;
}
__device__ __forceinline__ float lrelu(float f){ return f > 0.f ? f : LEAKY*f; }
__device__ __forceinline__ float4 lrelu4(float s, float4 t){
    float4 r; r.x = lrelu(s+t.x); r.y = lrelu(s+t.y); r.z = lrelu(s+t.z); r.w = lrelu(s+t.w); return r;
}
__device__ __forceinline__ float vmax4(float4 v){ return fmaxf(fmaxf(v.x,v.y), fmaxf(v.z,v.w)); }
__device__ __forceinline__ float vsum4(float4 v){ return v.x+v.y+v.z+v.w; }
__device__ __forceinline__ float4 exp4(float4 a, float mx){
    float4 r; r.x = __expf(a.x-mx); r.y = __expf(a.y-mx); r.z = __expf(a.z-mx); r.w = __expf(a.w-mx); return r;
}

// ws layout (floats): wv[12*64]@0 | WspT0[12*64]@768 | WspT1[5*64]@1536 | WtpT0[32*64]@1856 | WtpT1[16*64]@3904
__global__ void prep_kernel(const float* __restrict__ W,
    const float* a0, const float* a1, const float* a2,  const float* a3,
    const float* a4, const float* a5, const float* a6,  const float* a7,
    const float* a8, const float* a9, const float* a10, const float* a11,
    const float* __restrict__ Wsp0, const float* __restrict__ Wsp1,
    const float* __restrict__ Wtp0, const float* __restrict__ Wtp1,
    float* __restrict__ ws)
{
    int blk = blockIdx.x, t = threadIdx.x;
    if (blk < 12) {
        const float* as[12] = {a0,a1,a2,a3,a4,a5,a6,a7,a8,a9,a10,a11};
        const float* a = as[blk];
        float s = 0.f;
        #pragma unroll
        for (int h = 0; h < 128; ++h) s += W[t*128 + h] * a[h];
        ws[blk*64 + t] = s;
    } else if (blk == 12) {
        for (int i = t; i < 768; i += 64) { int k = i >> 6, c = i & 63; ws[768 + i] = Wsp0[c*12 + k]; }
    } else if (blk == 13) {
        for (int i = t; i < 320; i += 64) { int k = i >> 6, c = i & 63; ws[1536 + i] = Wsp1[c*5 + k]; }
    } else if (blk == 14) {
        for (int i = t; i < 2048; i += 64) { int k = i >> 6, c = i & 63; ws[1856 + i] = Wtp0[c*32 + k]; }
    } else {
        for (int i = t; i < 1024; i += 64) { int k = i >> 6, c = i & 63; ws[3904 + i] = Wtp1[c*16 + k]; }
    }
}

// ================== TEMPORAL: 6400 graphs of 64 nodes, 512 threads ==================
// R2-proven config: (512,4) compiles to 64 VGPR spill-free -> 2 blocks/CU resident,
// occupancy ~45%, 360 us. Full-width 1-output/thread phases.
__global__ __launch_bounds__(512, 4)
void temporal_kernel(const float* __restrict__ src, const float* __restrict__ wvec_g,
                     const float* __restrict__ Wp0, const float* __restrict__ b0,
                     const float* __restrict__ Wp1, const float* __restrict__ b1,
                     float* __restrict__ out, int nwg8)
{
    constexpr int NT = 512;
    // strides: CP=68, A0P=68, N1R=36, N2R=20
    constexpr int oA1 = 0;          // [32][36]
    constexpr int oP1 = 1152;       // [32][20]
    constexpr int oS1 = 1792;       // [32][20]
    constexpr int oA2 = 2432;       // [16][20]
    constexpr int oS01 = 2752;      // [64][20]

    __shared__ __align__(16) float xr[4352];   // x0[64][68]; tenants after x0 dies
    __shared__ __align__(16) float A0[4352];   // attn0 -> fusion (in place) [64][68]
    __shared__ __align__(16) float PR[2304];   // P0[64][36]... -> x1[32][68] -> M1[64][36] -> M2[64][20]
    __shared__ __align__(16) float S0[2304];   // [64][36]
    __shared__ __align__(16) float sv[64], tv[64], rx[64], rs[64];
    __shared__ __align__(16) float wv[384];

    const int tid = threadIdx.x;
    const int g = (blockIdx.x & 7) * nwg8 + (blockIdx.x >> 3);
    const int b = g / 25, inner = g - b*25;

    for (int i = tid; i < 384; i += NT) wv[i] = wvec_g[i];
    // load x0[r][c] from src[b][c][r][inner] (inner = joint, stride 1)
    for (int i = tid; i < 4096; i += NT) {
        int c = i >> 6, r = i & 63;
        xr[r*68 + c] = src[((size_t)(b*64 + c)*64 + r)*25 + inner];
    }
    __syncthreads();

    // ---- phase 1: {s0,t0 | P0 = x0@Wp0} ----
    for (int i = tid; i < 128; i += NT) {
        int which = i >> 6, p = i & 63;
        const float* w = wv + which*64;
        float acc = 0.f;
        #pragma unroll
        for (int c = 0; c < 64; c += 4) acc += dot4(ldf4(&xr[p*68 + c]), ldf4(&w[c]));
        if (which) tv[p] = acc; else sv[p] = acc;
    }
    for (int i = tid; i < 512; i += NT) {
        int p = i >> 3, k4 = i & 7;
        float4 acc = {0,0,0,0};
        #pragma unroll
        for (int c = 0; c < 64; ++c) acc = fma4(xr[p*68 + c], ldf4(&Wp0[c*32 + 4*k4]), acc);
        stf4(&PR[p*36 + 4*k4], acc);
    }
    __syncthreads();

    // ---- phase 2: A0 = leaky(s+t^T) ----
    for (int i = tid; i < 1024; i += NT) {
        int p = i >> 4, q4 = i & 15;
        stf4(&A0[p*68 + 4*q4], lrelu4(sv[p], ldf4(&tv[4*q4])));
    }
    __syncthreads();

    // ---- phase 3: S0raw = A0 @ P0 + b0 ----
    for (int i = tid; i < 512; i += NT) {
        int p = i >> 3, k4 = i & 7;
        float4 acc = ldf4(&b0[4*k4]);
        #pragma unroll
        for (int m = 0; m < 64; ++m) acc = fma4(A0[p*68 + m], ldf4(&PR[m*36 + 4*k4]), acc);
        stf4(&S0[p*36 + 4*k4], acc);
    }
    __syncthreads();

    // ---- phase 4: row softmax S0 ----
    for (int p = tid; p < 64; p += NT) {
        float mx = -1e30f;
        #pragma unroll
        for (int k = 0; k < 32; ++k) mx = fmaxf(mx, S0[p*36 + k]);
        float sm = 0.f;
        #pragma unroll
        for (int k = 0; k < 32; ++k) { float e = __expf(S0[p*36 + k] - mx); S0[p*36 + k] = e; sm += e; }
        float inv = 1.f/sm;
        #pragma unroll
        for (int k = 0; k < 32; ++k) S0[p*36 + k] *= inv;
    }
    __syncthreads();

    // ---- phase 5: x1 = S0^T @ x0 (into PR, stride 68) ----
    for (int i = tid; i < 512; i += NT) {
        int k = i >> 4, c4 = i & 15;
        float4 acc = {0,0,0,0};
        #pragma unroll
        for (int p = 0; p < 64; ++p) acc = fma4(S0[p*36 + k], ldf4(&xr[p*68 + 4*c4]), acc);
        stf4(&PR[k*68 + 4*c4], acc);
    }
    __syncthreads();

    // ---- phase 6: {s1,t1 | P1 = x1@Wp1} ----
    for (int i = tid; i < 64; i += NT) {
        int which = i >> 5, p = i & 31;
        const float* w = wv + (2 + which)*64;
        float acc = 0.f;
        #pragma unroll
        for (int c = 0; c < 64; c += 4) acc += dot4(ldf4(&PR[p*68 + c]), ldf4(&w[c]));
        if (which) tv[p] = acc; else sv[p] = acc;
    }
    for (int i = tid; i < 128; i += NT) {
        int p = i >> 2, k4 = i & 3;
        float4 acc = {0,0,0,0};
        #pragma unroll
        for (int c = 0; c < 64; ++c) acc = fma4(PR[p*68 + c], ldf4(&Wp1[c*16 + 4*k4]), acc);
        stf4(&xr[oP1 + p*20 + 4*k4], acc);
    }
    __syncthreads();

    // ---- phase 7: A1 ----
    for (int i = tid; i < 1024; i += NT) {
        int p = i >> 5, q = i & 31;
        xr[oA1 + p*36 + q] = lrelu(sv[p] + tv[q]);
    }
    __syncthreads();

    // ---- phase 8: S1raw = A1@P1 + b1 ----
    for (int i = tid; i < 128; i += NT) {
        int p = i >> 2, k4 = i & 3;
        float4 acc = ldf4(&b1[4*k4]);
        #pragma unroll
        for (int m = 0; m < 32; ++m) acc = fma4(xr[oA1 + p*36 + m], ldf4(&xr[oP1 + m*20 + 4*k4]), acc);
        stf4(&xr[oS1 + p*20 + 4*k4], acc);
    }
    __syncthreads();

    // ---- phase 9: {row softmax S1 | u,v = x1 . ws2/wd2} ----
    for (int p = tid; p < 32; p += NT) {
        float mx = -1e30f;
        #pragma unroll
        for (int k = 0; k < 16; ++k) mx = fmaxf(mx, xr[oS1 + p*20 + k]);
        float sm = 0.f;
        #pragma unroll
        for (int k = 0; k < 16; ++k) { float e = __expf(xr[oS1 + p*20 + k] - mx); xr[oS1 + p*20 + k] = e; sm += e; }
        float inv = 1.f/sm;
        #pragma unroll
        for (int k = 0; k < 16; ++k) xr[oS1 + p*20 + k] *= inv;
    }
    for (int i = tid; i < 64; i += NT) {
        int which = i >> 5, p = i & 31;
        const float* w = wv + (4 + which)*64;
        float acc = 0.f;
        #pragma unroll
        for (int c = 0; c < 64; c += 4) acc += dot4(ldf4(&PR[p*68 + c]), ldf4(&w[c]));
        if (which) tv[p] = acc; else sv[p] = acc;
    }
    __syncthreads();

    // ---- phase 10: rx/rs = S1^T . (u,v) ----
    for (int k = tid; k < 16; k += NT) {
        float a = 0.f, c2 = 0.f;
        #pragma unroll
        for (int n = 0; n < 32; ++n) { float s1 = xr[oS1 + n*20 + k]; a += s1*sv[n]; c2 += s1*tv[n]; }
        rx[k] = a; rs[k] = c2;
    }
    __syncthreads();

    // ---- phase 11: {A2 | M1 = S0@A1 (into PR)} ----
    for (int i = tid; i < 256; i += NT) {
        int p = i >> 4, q = i & 15;
        xr[oA2 + p*20 + q] = lrelu(rx[p] + rs[q]);
    }
    for (int i = tid; i < 512; i += NT) {
        int p = i >> 3, k4 = i & 7;
        float4 acc = {0,0,0,0};
        #pragma unroll
        for (int m = 0; m < 32; ++m) acc = fma4(S0[p*36 + m], ldf4(&xr[oA1 + m*36 + 4*k4]), acc);
        stf4(&PR[p*36 + 4*k4], acc);
    }
    __syncthreads();

    // ---- phase 12: {fusion += M1@S0^T | S01 = S0@S1} ----
    {
        int q = tid & 63, pg = tid >> 6;
        float4 s0r[8];
        #pragma unroll
        for (int j = 0; j < 8; ++j) s0r[j] = ldf4(&S0[q*36 + 4*j]);
        #pragma unroll
        for (int pi = 0; pi < 8; ++pi) {
            int p = pg*8 + pi;
            float acc = 0.f;
            #pragma unroll
            for (int j = 0; j < 8; ++j) acc += dot4(ldf4(&PR[p*36 + 4*j]), s0r[j]);
            A0[p*68 + q] += acc;
        }
    }
    for (int i = tid; i < 256; i += NT) {
        int p = i >> 2, k4 = i & 3;
        float4 acc = {0,0,0,0};
        #pragma unroll
        for (int m = 0; m < 32; ++m) acc = fma4(S0[p*36 + m], ldf4(&xr[oS1 + m*20 + 4*k4]), acc);
        stf4(&xr[oS01 + p*20 + 4*k4], acc);
    }
    __syncthreads();

    // ---- phase 13: M2 = S01 @ A2 (into PR) ----
    for (int i = tid; i < 256; i += NT) {
        int p = i >> 2, k4 = i & 3;
        float4 acc = {0,0,0,0};
        #pragma unroll
        for (int m = 0; m < 16; ++m) acc = fma4(xr[oS01 + p*20 + m], ldf4(&xr[oA2 + m*20 + 4*k4]), acc);
        stf4(&PR[p*20 + 4*k4], acc);
    }
    __syncthreads();

    // ---- phase 14: fusion += M2@S01^T ----
    {
        int q = tid & 63, pg = tid >> 6;
        float4 sr[4];
        #pragma unroll
        for (int j = 0; j < 4; ++j) sr[j] = ldf4(&xr[oS01 + q*20 + 4*j]);
        #pragma unroll
        for (int pi = 0; pi < 8; ++pi) {
            int p = pg*8 + pi;
            float acc = 0.f;
            #pragma unroll
            for (int j = 0; j < 4; ++j) acc += dot4(ldf4(&PR[p*20 + 4*j]), sr[j]);
            A0[p*68 + q] += acc;
        }
    }
    __syncthreads();

    // ---- phase 15: final row-softmax stats ----
    for (int p = tid; p < 64; p += NT) {
        float mx = -1e30f;
        #pragma unroll
        for (int q = 0; q < 64; ++q) mx = fmaxf(mx, A0[p*68 + q]);
        float sm = 0.f;
        #pragma unroll
        for (int q = 0; q < 64; ++q) sm += __expf(A0[p*68 + q] - mx);
        rx[p] = mx; rs[p] = 1.f/sm;
    }
    __syncthreads();

    // ---- phase 16: write ----
    {
        size_t base = (size_t)g * 4096;
        for (int i = tid; i < 1024; i += NT) {
            int p = i >> 4, q4 = i & 15;
            float mx = rx[p], inv = rs[p];
            float4 a = exp4(ldf4(&A0[p*68 + 4*q4]), mx);
            a.x *= inv; a.y *= inv; a.z *= inv; a.w *= inv;
            stf4(&out[base + p*64 + 4*q4], a);
        }
    }
}

// ================== SPATIAL: 16384 graphs of 25 nodes, 256 threads ==================
__global__ __launch_bounds__(256, 4)
void spatial_kernel(const float* __restrict__ src, const float* __restrict__ wvg,
                    const float* __restrict__ WpT0, const float* __restrict__ WpT1,
                    const float* __restrict__ b0, const float* __restrict__ b1,
                    float* __restrict__ out, int nwg8)
{
    __shared__ __align__(16) float Rx0[1700];   // x0[25][68]; then tenants
    __shared__ __align__(16) float RA0[700];    // A0/fusion [25][28]
    __shared__ __align__(16) float RPR[816];    // P0T[12][28] -> x1[12][68] -> M1[25][20] -> M2[25][12]
    __shared__ __align__(16) float RS0[500];    // S0[25][20]
    __shared__ __align__(16) float sv[32], tv[32], ua[32], va[32], rxa[8], rsa[8];

    float* x0  = Rx0;
    float* A1  = Rx0;          // [12][20]
    float* A1T = Rx0 + 240;    // [12][20]
    float* P1T = Rx0 + 480;    // [5][12]
    float* S1  = Rx0 + 540;    // [12][12]
    float* S1T = Rx0 + 684;    // [5][12]
    float* A2T = Rx0 + 744;    // [5][12]
    float* S01 = Rx0 + 804;    // [25][12]
    float* A0  = RA0;
    float* P0T = RPR;          // [12][28]
    float* x1  = RPR;          // [12][68]
    float* M1  = RPR;          // [25][20]
    float* M2  = RPR;          // [25][12]
    float* S0  = RS0;          // [25][20]

    const int t = threadIdx.x;
    const int g = (blockIdx.x & 7) * nwg8 + (blockIdx.x >> 3);
    const int b = g >> 6, inner = g & 63;
    const float* srcb = src + (size_t)b*102400 + inner*25;  // + c*1600 + r  (inner = timestep, stride 25)

    // ---- L ----
    for (int i = t; i < 400; i += 256) {
        int r = i % 25, c0 = (i / 25) << 2;
        float4 v;
        v.x = srcb[(c0+0)*1600 + r];
        v.y = srcb[(c0+1)*1600 + r];
        v.z = srcb[(c0+2)*1600 + r];
        v.w = srcb[(c0+3)*1600 + r];
        stf4(&x0[r*68 + c0], v);
    }
    __syncthreads();

    // ---- P0: dots || P0T (zero-padded cols 25..27) ----
    if (t < 50) {
        int which = t / 25, p = t - which*25;
        const float* w = wvg + which*64;
        float a = 0.f;
        #pragma unroll
        for (int c4 = 0; c4 < 16; ++c4) a += dot4(ldf4(&x0[p*68 + 4*c4]), ldf4(&w[4*c4]));
        if (which) tv[p] = a; else sv[p] = a;
    }
    for (int i = t; i < 336; i += 256) {
        int k = i / 28, m = i - k*28;
        float a = 0.f;
        if (m < 25) {
            #pragma unroll
            for (int c4 = 0; c4 < 16; ++c4) a += dot4(ldf4(&WpT0[k*64 + 4*c4]), ldf4(&x0[m*68 + 4*c4]));
        }
        P0T[k*28 + m] = a;
    }
    __syncthreads();

    // ---- P1: A0 (pads = -1e30) ----
    for (int i = t; i < 700; i += 256) {
        int p = i / 28, q = i - p*28;
        A0[i] = (q < 25) ? lrelu(sv[p] + tv[q]) : -1e30f;
    }
    __syncthreads();

    // ---- P2: S0raw ----
    for (int i = t; i < 300; i += 256) {
        int p = i / 12, k = i - p*12;
        float acc = b0[k];
        #pragma unroll
        for (int m4 = 0; m4 < 7; ++m4) acc += dot4(ldf4(&A0[p*28 + 4*m4]), ldf4(&P0T[k*28 + 4*m4]));
        S0[p*20 + k] = acc;
    }
    __syncthreads();

    // ---- P3: softmax S0 rows ----
    if (t < 25) {
        float4 r[3]; float mx = -1e30f;
        #pragma unroll
        for (int u = 0; u < 3; ++u) { r[u] = ldf4(&S0[t*20 + 4*u]); mx = fmaxf(mx, vmax4(r[u])); }
        float sm = 0.f;
        #pragma unroll
        for (int u = 0; u < 3; ++u) { r[u] = exp4(r[u], mx); sm += vsum4(r[u]); }
        float inv = 1.f/sm;
        #pragma unroll
        for (int u = 0; u < 3; ++u) {
            r[u].x *= inv; r[u].y *= inv; r[u].z *= inv; r[u].w *= inv;
            stf4(&S0[t*20 + 4*u], r[u]);
        }
    }
    __syncthreads();

    // ---- P4: x1[k][c] ----
    if (t < 96) {
        int k = t >> 3, c0 = (t & 7) << 3;
        float4 a = {0,0,0,0}, bb = {0,0,0,0};
        #pragma unroll
        for (int p = 0; p < 25; ++p) {
            float s = S0[p*20 + k];
            a  = fma4(s, ldf4(&x0[p*68 + c0]), a);
            bb = fma4(s, ldf4(&x0[p*68 + c0 + 4]), bb);
        }
        stf4(&x1[k*68 + c0], a);
        stf4(&x1[k*68 + c0 + 4], bb);
    }
    __syncthreads();

    // ---- P5: dots || P1T ----
    if (t < 48) {
        int which = t / 12, p = t - which*12;
        const float* w = wvg + (2+which)*64;
        float a = 0.f;
        #pragma unroll
        for (int c4 = 0; c4 < 16; ++c4) a += dot4(ldf4(&x1[p*68 + 4*c4]), ldf4(&w[4*c4]));
        if (which == 0) sv[p] = a; else if (which == 1) tv[p] = a;
        else if (which == 2) ua[p] = a; else va[p] = a;
    }
    for (int i = t; i < 60; i += 256) {
        int j = i / 12, k = i - j*12;
        float a = 0.f;
        #pragma unroll
        for (int c4 = 0; c4 < 16; ++c4) a += dot4(ldf4(&WpT1[j*64 + 4*c4]), ldf4(&x1[k*68 + 4*c4]));
        P1T[j*12 + k] = a;
    }
    __syncthreads();

    // ---- P6: A1, A1T ----
    for (int i = t; i < 288; i += 256) {
        int mat = i / 144, rr = (i - mat*144) / 12, q = i % 12;
        if (mat == 0) A1 [rr*20 + q] = lrelu(sv[rr] + tv[q]);
        else          A1T[rr*20 + q] = lrelu(sv[q] + tv[rr]);
    }
    __syncthreads();

    // ---- G1: M1 || S1raw ----
    for (int i = t; i < 300; i += 256) {
        int p = i / 12, k = i - p*12;
        float acc = 0.f;
        #pragma unroll
        for (int m4 = 0; m4 < 3; ++m4) acc += dot4(ldf4(&S0[p*20 + 4*m4]), ldf4(&A1T[k*20 + 4*m4]));
        M1[p*20 + k] = acc;
    }
    for (int i = t; i < 60; i += 256) {
        int m = i / 5, j = i - m*5;
        float acc = b1[j];
        #pragma unroll
        for (int k4 = 0; k4 < 3; ++k4) acc += dot4(ldf4(&A1[m*20 + 4*k4]), ldf4(&P1T[j*12 + 4*k4]));
        S1[m*12 + j] = acc;
    }
    __syncthreads();

    // ---- G2a: softmax S1 || fusion pass1 ----
    if (t < 12) {
        float mx = -1e30f;
        float r0 = S1[t*12+0], r1 = S1[t*12+1], r2 = S1[t*12+2], r3 = S1[t*12+3], r4 = S1[t*12+4];
        mx = fmaxf(fmaxf(fmaxf(r0,r1), fmaxf(r2,r3)), r4);
        r0 = __expf(r0-mx); r1 = __expf(r1-mx); r2 = __expf(r2-mx); r3 = __expf(r3-mx); r4 = __expf(r4-mx);
        float inv = 1.f/(r0+r1+r2+r3+r4);
        S1[t*12+0] = r0*inv; S1[t*12+1] = r1*inv; S1[t*12+2] = r2*inv; S1[t*12+3] = r3*inv; S1[t*12+4] = r4*inv;
    }
    for (int i = t; i < 625; i += 256) {
        int p = i / 25, q = i - p*25;
        float acc = A0[p*28 + q];
        #pragma unroll
        for (int m4 = 0; m4 < 3; ++m4) acc += dot4(ldf4(&M1[p*20 + 4*m4]), ldf4(&S0[q*20 + 4*m4]));
        A0[p*28 + q] = acc;
    }
    __syncthreads();

    // ---- G2b: S1T || rxa/rsa ----
    for (int i = t; i < 60; i += 256) {
        int j = i / 12, m = i - j*12;
        S1T[j*12 + m] = S1[m*12 + j];
    }
    if (t >= 64 && t < 74) {
        int tp = t - 64, which = tp / 5, k = tp - which*5;
        float a = 0.f;
        #pragma unroll
        for (int n = 0; n < 12; ++n) a += S1[n*12 + k] * (which ? va[n] : ua[n]);
        if (which) rsa[k] = a; else rxa[k] = a;
    }
    __syncthreads();

    // ---- G3: A2T (zero-padded) || S01 (zero-padded) ----
    for (int i = t; i < 40; i += 256) {
        int q = i >> 3, p = i & 7;
        A2T[q*12 + p] = (p < 5) ? lrelu(rxa[p] + rsa[q]) : 0.f;
    }
    for (int i = t; i < 200; i += 256) {
        int p = i >> 3, c = i & 7;
        float acc = 0.f;
        if (c < 5) {
            #pragma unroll
            for (int m4 = 0; m4 < 3; ++m4) acc += dot4(ldf4(&S0[p*20 + 4*m4]), ldf4(&S1T[c*12 + 4*m4]));
        }
        S01[p*12 + c] = acc;
    }
    __syncthreads();

    // ---- G4: M2 (zero-padded) ----
    for (int i = t; i < 200; i += 256) {
        int p = i >> 3, k = i & 7;
        float acc = 0.f;
        if (k < 5) {
            #pragma unroll
            for (int m4 = 0; m4 < 2; ++m4) acc += dot4(ldf4(&S01[p*12 + 4*m4]), ldf4(&A2T[k*12 + 4*m4]));
        }
        M2[p*12 + k] = acc;
    }
    __syncthreads();

    // ---- G5: fusion pass2 ----
    for (int i = t; i < 625; i += 256) {
        int p = i / 25, q = i - p*25;
        float acc = A0[p*28 + q];
        #pragma unroll
        for (int m4 = 0; m4 < 2; ++m4) acc += dot4(ldf4(&M2[p*12 + 4*m4]), ldf4(&S01[q*12 + 4*m4]));
        A0[p*28 + q] = acc;
    }
    __syncthreads();

    // ---- P13: stats ----
    if (t < 25) {
        float4 r[7]; float mx = -1e30f;
        #pragma unroll
        for (int u = 0; u < 7; ++u) { r[u] = ldf4(&A0[t*28 + 4*u]); mx = fmaxf(mx, vmax4(r[u])); }
        float sm = 0.f;
        #pragma unroll
        for (int u = 0; u < 7; ++u) sm += vsum4(exp4(r[u], mx));
        sv[t] = mx; tv[t] = 1.f/sm;
    }
    __syncthreads();

    // ---- P14 ----
    for (int i = t; i < 625; i += 256) {
        int p = i / 25, q = i - p*25;
        out[(size_t)g*625 + i] = __expf(A0[p*28 + q] - sv[p]) * tv[p];
    }
}

extern "C" void kernel_launch(void* const* d_in, const int* in_sizes, int n_in,
                              void* d_out, int out_size, void* d_ws, size_t ws_size,
                              hipStream_t stream) {
    const float* src = (const float*)d_in[0];
    const float* W   = (const float*)d_in[1];
    float* ws = (float*)d_ws;

    prep_kernel<<<16, 64, 0, stream>>>(W,
        (const float*)d_in[2],  (const float*)d_in[3],    // as_src0, as_dst0
        (const float*)d_in[6],  (const float*)d_in[7],    // as_src1, as_dst1
        (const float*)d_in[10], (const float*)d_in[11],   // as_src2, as_dst2
        (const float*)d_in[4],  (const float*)d_in[5],    // at_src0, at_dst0
        (const float*)d_in[8],  (const float*)d_in[9],    // at_src1, at_dst1
        (const float*)d_in[12], (const float*)d_in[13],   // at_src2, at_dst2
        (const float*)d_in[14], (const float*)d_in[16],   // Wsp0, Wsp1
        (const float*)d_in[18], (const float*)d_in[20],   // Wtp0, Wtp1
        ws);

    float* out = (float*)d_out;
    spatial_kernel<<<16384, 256, 0, stream>>>(
        src, ws, ws + 768, ws + 1536,
        (const float*)d_in[15], (const float*)d_in[17],
        out, 16384/8);
    temporal_kernel<<<6400, 512, 0, stream>>>(
        src, ws + 384,
        (const float*)d_in[18], (const float*)d_in[19],   // Wtp0 (raw), btp0
        (const float*)d_in[20], (const float*)d_in[21],   // Wtp1 (raw), btp1
        out + 10240000, 6400/8);
}

// Round 9
// 496.386 us; speedup vs baseline: 1.9346x; 1.0390x over previous
//
#include <hip/hip_runtime.h>
#include <math.h>

constexpr float LEAKY = 0.2f;

__device__ __forceinline__ float4 ldf4(const float* p){ return *reinterpret_cast<const float4*>(p); }
__device__ __forceinline__ void stf4(float* p, float4 v){ *reinterpret_cast<float4*>(p) = v; }
__device__ __forceinline__ float dot4(float4 a, float4 b){ return a.x*b.x + a.y*b.y + a.z*b.z + a.w*b.w; }
__device__ __forceinline__ float4 fma4(float s, float4 b, float4 acc){
    acc.x += s*b.x; acc.y += s*b.y; acc.z += s*b.z; acc.w += s*b.w; return acc;
}
__device__ __forceinline__ float lrelu(float f){ return f > 0.f ? f : LEAKY*f; }
__device__ __forceinline__ float4 lrelu4(float s, float4 t){
    float4 r; r.x = lrelu(s+t.x); r.y = lrelu(s+t.y); r.z = lrelu(s+t.z); r.w = lrelu(s+t.w); return r;
}
__device__ __forceinline__ float vmax4(float4 v){ return fmaxf(fmaxf(v.x,v.y), fmaxf(v.z,v.w)); }
__device__ __forceinline__ float vsum4(float4 v){ return v.x+v.y+v.z+v.w; }
__device__ __forceinline__ float4 exp4(float4 a, float mx){
    float4 r; r.x = __expf(a.x-mx); r.y = __expf(a.y-mx); r.z = __expf(a.z-mx); r.w = __expf(a.w-mx); return r;
}

// ws layout (floats): wv[12*64]@0 | WspT0[12*64]@768 | WspT1[5*64]@1536 | WtpT0[32*64]@1856 | WtpT1[16*64]@3904
__global__ void prep_kernel(const float* __restrict__ W,
    const float* a0, const float* a1, const float* a2,  const float* a3,
    const float* a4, const float* a5, const float* a6,  const float* a7,
    const float* a8, const float* a9, const float* a10, const float* a11,
    const float* __restrict__ Wsp0, const float* __restrict__ Wsp1,
    const float* __restrict__ Wtp0, const float* __restrict__ Wtp1,
    float* __restrict__ ws)
{
    int blk = blockIdx.x, t = threadIdx.x;
    if (blk < 12) {
        const float* as[12] = {a0,a1,a2,a3,a4,a5,a6,a7,a8,a9,a10,a11};
        const float* a = as[blk];
        float s = 0.f;
        #pragma unroll
        for (int h = 0; h < 128; ++h) s += W[t*128 + h] * a[h];
        ws[blk*64 + t] = s;
    } else if (blk == 12) {
        for (int i = t; i < 768; i += 64) { int k = i >> 6, c = i & 63; ws[768 + i] = Wsp0[c*12 + k]; }
    } else if (blk == 13) {
        for (int i = t; i < 320; i += 64) { int k = i >> 6, c = i & 63; ws[1536 + i] = Wsp1[c*5 + k]; }
    } else if (blk == 14) {
        for (int i = t; i < 2048; i += 64) { int k = i >> 6, c = i & 63; ws[1856 + i] = Wtp0[c*32 + k]; }
    } else {
        for (int i = t; i < 1024; i += 64) { int k = i >> 6, c = i & 63; ws[3904 + i] = Wtp1[c*16 + k]; }
    }
}

// ================== TEMPORAL: 6400 graphs of 64 nodes, 512 threads ==================
// R2-proven base (64 VGPR, 2 blocks/CU, 16 waves). R9: k8-tiled phases 3/5,
// wave-parallel softmaxes (P4/P9), fused stats+write epilogue. LDS-pipe-bound.
__global__ __launch_bounds__(512, 4)
void temporal_kernel(const float* __restrict__ src, const float* __restrict__ wvec_g,
                     const float* __restrict__ Wp0, const float* __restrict__ b0,
                     const float* __restrict__ Wp1, const float* __restrict__ b1,
                     float* __restrict__ out, int nwg8)
{
    constexpr int NT = 512;
    constexpr int oA1 = 0;          // [32][36]
    constexpr int oP1 = 1152;       // [32][20]
    constexpr int oS1 = 1792;       // [32][20]
    constexpr int oA2 = 2432;       // [16][20]
    constexpr int oS01 = 2752;      // [64][20]

    __shared__ __align__(16) float xr[4352];   // x0[64][68]; tenants after x0 dies
    __shared__ __align__(16) float A0[4352];   // attn0 -> fusion (in place) [64][68]
    __shared__ __align__(16) float PR[2304];   // P0[64][36] -> x1[32][68] -> M1[64][36] -> M2[64][20]
    __shared__ __align__(16) float S0[2304];   // [64][36]
    __shared__ __align__(16) float sv[64], tv[64], rx[64], rs[64];
    __shared__ __align__(16) float wv[384];

    const int tid = threadIdx.x;
    const int g = (blockIdx.x & 7) * nwg8 + (blockIdx.x >> 3);
    const int b = g / 25, inner = g - b*25;

    for (int i = tid; i < 384; i += NT) wv[i] = wvec_g[i];
    for (int i = tid; i < 4096; i += NT) {
        int c = i >> 6, r = i & 63;
        xr[r*68 + c] = src[((size_t)(b*64 + c)*64 + r)*25 + inner];
    }
    __syncthreads();

    // ---- phase 1: {s0,t0 | P0 = x0@Wp0} ----
    for (int i = tid; i < 128; i += NT) {
        int which = i >> 6, p = i & 63;
        const float* w = wv + which*64;
        float acc = 0.f;
        #pragma unroll
        for (int c = 0; c < 64; c += 4) acc += dot4(ldf4(&xr[p*68 + c]), ldf4(&w[c]));
        if (which) tv[p] = acc; else sv[p] = acc;
    }
    for (int i = tid; i < 512; i += NT) {
        int p = i >> 3, k4 = i & 7;
        float4 acc = {0,0,0,0};
        #pragma unroll
        for (int c = 0; c < 64; ++c) acc = fma4(xr[p*68 + c], ldf4(&Wp0[c*32 + 4*k4]), acc);
        stf4(&PR[p*36 + 4*k4], acc);
    }
    __syncthreads();

    // ---- phase 2: A0 = leaky(s+t^T) ----
    for (int i = tid; i < 1024; i += NT) {
        int p = i >> 4, q4 = i & 15;
        stf4(&A0[p*68 + 4*q4], lrelu4(sv[p], ldf4(&tv[4*q4])));
    }
    __syncthreads();

    // ---- phase 3: S0raw = A0 @ P0 + b0 (k8 tiles: 256 thr x 8 floats) ----
    if (tid < 256) {
        int p = tid >> 2, k8 = tid & 3;
        float4 acc0 = ldf4(&b0[8*k8]);
        float4 acc1 = ldf4(&b0[8*k8 + 4]);
        #pragma unroll
        for (int m = 0; m < 64; ++m) {
            float a = A0[p*68 + m];
            acc0 = fma4(a, ldf4(&PR[m*36 + 8*k8]), acc0);
            acc1 = fma4(a, ldf4(&PR[m*36 + 8*k8 + 4]), acc1);
        }
        stf4(&S0[p*36 + 8*k8], acc0);
        stf4(&S0[p*36 + 8*k8 + 4], acc1);
    }
    __syncthreads();

    // ---- phase 4: row softmax S0 (8 lanes/row, all 512 threads) ----
    {
        int p = tid >> 3, l = tid & 7;
        float4 v = ldf4(&S0[p*36 + 4*l]);
        float mx = vmax4(v);
        mx = fmaxf(mx, __shfl_xor(mx,1)); mx = fmaxf(mx, __shfl_xor(mx,2)); mx = fmaxf(mx, __shfl_xor(mx,4));
        v = exp4(v, mx);
        float sm = vsum4(v);
        sm += __shfl_xor(sm,1); sm += __shfl_xor(sm,2); sm += __shfl_xor(sm,4);
        float inv = 1.f/sm;
        v.x *= inv; v.y *= inv; v.z *= inv; v.w *= inv;
        stf4(&S0[p*36 + 4*l], v);
    }
    __syncthreads();

    // ---- phase 5: x1 = S0^T @ x0 (c8 tiles: 256 thr x 8 floats, into PR stride 68) ----
    if (tid < 256) {
        int k = tid >> 3, c8 = tid & 7;
        float4 acc0 = {0,0,0,0}, acc1 = {0,0,0,0};
        #pragma unroll
        for (int p = 0; p < 64; ++p) {
            float s = S0[p*36 + k];
            acc0 = fma4(s, ldf4(&xr[p*68 + 8*c8]), acc0);
            acc1 = fma4(s, ldf4(&xr[p*68 + 8*c8 + 4]), acc1);
        }
        stf4(&PR[k*68 + 8*c8], acc0);
        stf4(&PR[k*68 + 8*c8 + 4], acc1);
    }
    __syncthreads();

    // ---- phase 6: {s1,t1 | P1 = x1@Wp1} ----
    for (int i = tid; i < 64; i += NT) {
        int which = i >> 5, p = i & 31;
        const float* w = wv + (2 + which)*64;
        float acc = 0.f;
        #pragma unroll
        for (int c = 0; c < 64; c += 4) acc += dot4(ldf4(&PR[p*68 + c]), ldf4(&w[c]));
        if (which) tv[p] = acc; else sv[p] = acc;
    }
    for (int i = tid; i < 128; i += NT) {
        int p = i >> 2, k4 = i & 3;
        float4 acc = {0,0,0,0};
        #pragma unroll
        for (int c = 0; c < 64; ++c) acc = fma4(PR[p*68 + c], ldf4(&Wp1[c*16 + 4*k4]), acc);
        stf4(&xr[oP1 + p*20 + 4*k4], acc);
    }
    __syncthreads();

    // ---- phase 7: A1 ----
    for (int i = tid; i < 1024; i += NT) {
        int p = i >> 5, q = i & 31;
        xr[oA1 + p*36 + q] = lrelu(sv[p] + tv[q]);
    }
    __syncthreads();

    // ---- phase 8: S1raw = A1@P1 + b1 ----
    for (int i = tid; i < 128; i += NT) {
        int p = i >> 2, k4 = i & 3;
        float4 acc = ldf4(&b1[4*k4]);
        #pragma unroll
        for (int m = 0; m < 32; ++m) acc = fma4(xr[oA1 + p*36 + m], ldf4(&xr[oP1 + m*20 + 4*k4]), acc);
        stf4(&xr[oS1 + p*20 + 4*k4], acc);
    }
    __syncthreads();

    // ---- phase 9: {row softmax S1 (128 thr, 4 lanes/row) | u,v dots (thr 128..191)} ----
    if (tid < 128) {
        int m = tid >> 2, l = tid & 3;
        float4 v = ldf4(&xr[oS1 + m*20 + 4*l]);
        float mx = vmax4(v);
        mx = fmaxf(mx, __shfl_xor(mx,1)); mx = fmaxf(mx, __shfl_xor(mx,2));
        v = exp4(v, mx);
        float sm = vsum4(v);
        sm += __shfl_xor(sm,1); sm += __shfl_xor(sm,2);
        float inv = 1.f/sm;
        v.x *= inv; v.y *= inv; v.z *= inv; v.w *= inv;
        stf4(&xr[oS1 + m*20 + 4*l], v);
    } else if (tid < 192) {
        int i = tid - 128;
        int which = i >> 5, p = i & 31;
        const float* w = wv + (4 + which)*64;
        float acc = 0.f;
        #pragma unroll
        for (int c = 0; c < 64; c += 4) acc += dot4(ldf4(&PR[p*68 + c]), ldf4(&w[c]));
        if (which) tv[p] = acc; else sv[p] = acc;
    }
    __syncthreads();

    // ---- phase 10: rx/rs = S1^T . (u,v) ----
    for (int k = tid; k < 16; k += NT) {
        float a = 0.f, c2 = 0.f;
        #pragma unroll
        for (int n = 0; n < 32; ++n) { float s1 = xr[oS1 + n*20 + k]; a += s1*sv[n]; c2 += s1*tv[n]; }
        rx[k] = a; rs[k] = c2;
    }
    __syncthreads();

    // ---- phase 11: {A2 | M1 = S0@A1 (into PR)} ----
    for (int i = tid; i < 256; i += NT) {
        int p = i >> 4, q = i & 15;
        xr[oA2 + p*20 + q] = lrelu(rx[p] + rs[q]);
    }
    for (int i = tid; i < 512; i += NT) {
        int p = i >> 3, k4 = i & 7;
        float4 acc = {0,0,0,0};
        #pragma unroll
        for (int m = 0; m < 32; ++m) acc = fma4(S0[p*36 + m], ldf4(&xr[oA1 + m*36 + 4*k4]), acc);
        stf4(&PR[p*36 + 4*k4], acc);
    }
    __syncthreads();

    // ---- phase 12: {fusion += M1@S0^T | S01 = S0@S1} ----
    {
        int q = tid & 63, pg = tid >> 6;
        float4 s0r[8];
        #pragma unroll
        for (int j = 0; j < 8; ++j) s0r[j] = ldf4(&S0[q*36 + 4*j]);
        #pragma unroll
        for (int pi = 0; pi < 8; ++pi) {
            int p = pg*8 + pi;
            float acc = 0.f;
            #pragma unroll
            for (int j = 0; j < 8; ++j) acc += dot4(ldf4(&PR[p*36 + 4*j]), s0r[j]);
            A0[p*68 + q] += acc;
        }
    }
    for (int i = tid; i < 256; i += NT) {
        int p = i >> 2, k4 = i & 3;
        float4 acc = {0,0,0,0};
        #pragma unroll
        for (int m = 0; m < 32; ++m) acc = fma4(S0[p*36 + m], ldf4(&xr[oS1 + m*20 + 4*k4]), acc);
        stf4(&xr[oS01 + p*20 + 4*k4], acc);
    }
    __syncthreads();

    // ---- phase 13: M2 = S01 @ A2 (into PR) ----
    for (int i = tid; i < 256; i += NT) {
        int p = i >> 2, k4 = i & 3;
        float4 acc = {0,0,0,0};
        #pragma unroll
        for (int m = 0; m < 16; ++m) acc = fma4(xr[oS01 + p*20 + m], ldf4(&xr[oA2 + m*20 + 4*k4]), acc);
        stf4(&PR[p*20 + 4*k4], acc);
    }
    __syncthreads();

    // ---- phase 14: fusion += M2@S01^T ----
    {
        int q = tid & 63, pg = tid >> 6;
        float4 sr[4];
        #pragma unroll
        for (int j = 0; j < 4; ++j) sr[j] = ldf4(&xr[oS01 + q*20 + 4*j]);
        #pragma unroll
        for (int pi = 0; pi < 8; ++pi) {
            int p = pg*8 + pi;
            float acc = 0.f;
            #pragma unroll
            for (int j = 0; j < 4; ++j) acc += dot4(ldf4(&PR[p*20 + 4*j]), sr[j]);
            A0[p*68 + q] += acc;
        }
    }
    __syncthreads();

    // ---- phase 15+16 fused: row softmax of fusion + write (8 lanes/row, 512 thr) ----
    {
        int p = tid >> 3, l = tid & 7;
        float4 v1 = ldf4(&A0[p*68 + 4*l]);
        float4 v2 = ldf4(&A0[p*68 + 32 + 4*l]);
        float mx = fmaxf(vmax4(v1), vmax4(v2));
        mx = fmaxf(mx, __shfl_xor(mx,1)); mx = fmaxf(mx, __shfl_xor(mx,2)); mx = fmaxf(mx, __shfl_xor(mx,4));
        float4 e1 = exp4(v1, mx), e2 = exp4(v2, mx);
        float sm = vsum4(e1) + vsum4(e2);
        sm += __shfl_xor(sm,1); sm += __shfl_xor(sm,2); sm += __shfl_xor(sm,4);
        float inv = 1.f/sm;
        e1.x*=inv; e1.y*=inv; e1.z*=inv; e1.w*=inv;
        e2.x*=inv; e2.y*=inv; e2.z*=inv; e2.w*=inv;
        size_t base = (size_t)g*4096 + (size_t)p*64;
        stf4(&out[base + 4*l], e1);
        stf4(&out[base + 32 + 4*l], e2);
    }
}

// ================== SPATIAL: 16384 graphs of 25 nodes, 256 threads ==================
__global__ __launch_bounds__(256, 4)
void spatial_kernel(const float* __restrict__ src, const float* __restrict__ wvg,
                    const float* __restrict__ WpT0, const float* __restrict__ WpT1,
                    const float* __restrict__ b0, const float* __restrict__ b1,
                    float* __restrict__ out, int nwg8)
{
    __shared__ __align__(16) float Rx0[1700];
    __shared__ __align__(16) float RA0[700];
    __shared__ __align__(16) float RPR[816];
    __shared__ __align__(16) float RS0[500];
    __shared__ __align__(16) float sv[32], tv[32], ua[32], va[32], rxa[8], rsa[8];

    float* x0  = Rx0;
    float* A1  = Rx0;
    float* A1T = Rx0 + 240;
    float* P1T = Rx0 + 480;
    float* S1  = Rx0 + 540;
    float* S1T = Rx0 + 684;
    float* A2T = Rx0 + 744;
    float* S01 = Rx0 + 804;
    float* A0  = RA0;
    float* P0T = RPR;
    float* x1  = RPR;
    float* M1  = RPR;
    float* M2  = RPR;
    float* S0  = RS0;

    const int t = threadIdx.x;
    const int g = (blockIdx.x & 7) * nwg8 + (blockIdx.x >> 3);
    const int b = g >> 6, inner = g & 63;
    const float* srcb = src + (size_t)b*102400 + inner*25;

    for (int i = t; i < 400; i += 256) {
        int r = i % 25, c0 = (i / 25) << 2;
        float4 v;
        v.x = srcb[(c0+0)*1600 + r];
        v.y = srcb[(c0+1)*1600 + r];
        v.z = srcb[(c0+2)*1600 + r];
        v.w = srcb[(c0+3)*1600 + r];
        stf4(&x0[r*68 + c0], v);
    }
    __syncthreads();

    if (t < 50) {
        int which = t / 25, p = t - which*25;
        const float* w = wvg + which*64;
        float a = 0.f;
        #pragma unroll
        for (int c4 = 0; c4 < 16; ++c4) a += dot4(ldf4(&x0[p*68 + 4*c4]), ldf4(&w[4*c4]));
        if (which) tv[p] = a; else sv[p] = a;
    }
    for (int i = t; i < 336; i += 256) {
        int k = i / 28, m = i - k*28;
        float a = 0.f;
        if (m < 25) {
            #pragma unroll
            for (int c4 = 0; c4 < 16; ++c4) a += dot4(ldf4(&WpT0[k*64 + 4*c4]), ldf4(&x0[m*68 + 4*c4]));
        }
        P0T[k*28 + m] = a;
    }
    __syncthreads();

    for (int i = t; i < 700; i += 256) {
        int p = i / 28, q = i - p*28;
        A0[i] = (q < 25) ? lrelu(sv[p] + tv[q]) : -1e30f;
    }
    __syncthreads();

    for (int i = t; i < 300; i += 256) {
        int p = i / 12, k = i - p*12;
        float acc = b0[k];
        #pragma unroll
        for (int m4 = 0; m4 < 7; ++m4) acc += dot4(ldf4(&A0[p*28 + 4*m4]), ldf4(&P0T[k*28 + 4*m4]));
        S0[p*20 + k] = acc;
    }
    __syncthreads();

    if (t < 25) {
        float4 r[3]; float mx = -1e30f;
        #pragma unroll
        for (int u = 0; u < 3; ++u) { r[u] = ldf4(&S0[t*20 + 4*u]); mx = fmaxf(mx, vmax4(r[u])); }
        float sm = 0.f;
        #pragma unroll
        for (int u = 0; u < 3; ++u) { r[u] = exp4(r[u], mx); sm += vsum4(r[u]); }
        float inv = 1.f/sm;
        #pragma unroll
        for (int u = 0; u < 3; ++u) {
            r[u].x *= inv; r[u].y *= inv; r[u].z *= inv; r[u].w *= inv;
            stf4(&S0[t*20 + 4*u], r[u]);
        }
    }
    __syncthreads();

    if (t < 96) {
        int k = t >> 3, c0 = (t & 7) << 3;
        float4 a = {0,0,0,0}, bb = {0,0,0,0};
        #pragma unroll
        for (int p = 0; p < 25; ++p) {
            float s = S0[p*20 + k];
            a  = fma4(s, ldf4(&x0[p*68 + c0]), a);
            bb = fma4(s, ldf4(&x0[p*68 + c0 + 4]), bb);
        }
        stf4(&x1[k*68 + c0], a);
        stf4(&x1[k*68 + c0 + 4], bb);
    }
    __syncthreads();

    if (t < 48) {
        int which = t / 12, p = t - which*12;
        const float* w = wvg + (2+which)*64;
        float a = 0.f;
        #pragma unroll
        for (int c4 = 0; c4 < 16; ++c4) a += dot4(ldf4(&x1[p*68 + 4*c4]), ldf4(&w[4*c4]));
        if (which == 0) sv[p] = a; else if (which == 1) tv[p] = a;
        else if (which == 2) ua[p] = a; else va[p] = a;
    }
    for (int i = t; i < 60; i += 256) {
        int j = i / 12, k = i - j*12;
        float a = 0.f;
        #pragma unroll
        for (int c4 = 0; c4 < 16; ++c4) a += dot4(ldf4(&WpT1[j*64 + 4*c4]), ldf4(&x1[k*68 + 4*c4]));
        P1T[j*12 + k] = a;
    }
    __syncthreads();

    for (int i = t; i < 288; i += 256) {
        int mat = i / 144, rr = (i - mat*144) / 12, q = i % 12;
        if (mat == 0) A1 [rr*20 + q] = lrelu(sv[rr] + tv[q]);
        else          A1T[rr*20 + q] = lrelu(sv[q] + tv[rr]);
    }
    __syncthreads();

    for (int i = t; i < 300; i += 256) {
        int p = i / 12, k = i - p*12;
        float acc = 0.f;
        #pragma unroll
        for (int m4 = 0; m4 < 3; ++m4) acc += dot4(ldf4(&S0[p*20 + 4*m4]), ldf4(&A1T[k*20 + 4*m4]));
        M1[p*20 + k] = acc;
    }
    for (int i = t; i < 60; i += 256) {
        int m = i / 5, j = i - m*5;
        float acc = b1[j];
        #pragma unroll
        for (int k4 = 0; k4 < 3; ++k4) acc += dot4(ldf4(&A1[m*20 + 4*k4]), ldf4(&P1T[j*12 + 4*k4]));
        S1[m*12 + j] = acc;
    }
    __syncthreads();

    if (t < 12) {
        float mx = -1e30f;
        float r0 = S1[t*12+0], r1 = S1[t*12+1], r2 = S1[t*12+2], r3 = S1[t*12+3], r4 = S1[t*12+4];
        mx = fmaxf(fmaxf(fmaxf(r0,r1), fmaxf(r2,r3)), r4);
        r0 = __expf(r0-mx); r1 = __expf(r1-mx); r2 = __expf(r2-mx); r3 = __expf(r3-mx); r4 = __expf(r4-mx);
        float inv = 1.f/(r0+r1+r2+r3+r4);
        S1[t*12+0] = r0*inv; S1[t*12+1] = r1*inv; S1[t*12+2] = r2*inv; S1[t*12+3] = r3*inv; S1[t*12+4] = r4*inv;
    }
    for (int i = t; i < 625; i += 256) {
        int p = i / 25, q = i - p*25;
        float acc = A0[p*28 + q];
        #pragma unroll
        for (int m4 = 0; m4 < 3; ++m4) acc += dot4(ldf4(&M1[p*20 + 4*m4]), ldf4(&S0[q*20 + 4*m4]));
        A0[p*28 + q] = acc;
    }
    __syncthreads();

    for (int i = t; i < 60; i += 256) {
        int j = i / 12, m = i - j*12;
        S1T[j*12 + m] = S1[m*12 + j];
    }
    if (t >= 64 && t < 74) {
        int tp = t - 64, which = tp / 5, k = tp - which*5;
        float a = 0.f;
        #pragma unroll
        for (int n = 0; n < 12; ++n) a += S1[n*12 + k] * (which ? va[n] : ua[n]);
        if (which) rsa[k] = a; else rxa[k] = a;
    }
    __syncthreads();

    for (int i = t; i < 40; i += 256) {
        int q = i >> 3, p = i & 7;
        A2T[q*12 + p] = (p < 5) ? lrelu(rxa[p] + rsa[q]) : 0.f;
    }
    for (int i = t; i < 200; i += 256) {
        int p = i >> 3, c = i & 7;
        float acc = 0.f;
        if (c < 5) {
            #pragma unroll
            for (int m4 = 0; m4 < 3; ++m4) acc += dot4(ldf4(&S0[p*20 + 4*m4]), ldf4(&S1T[c*12 + 4*m4]));
        }
        S01[p*12 + c] = acc;
    }
    __syncthreads();

    for (int i = t; i < 200; i += 256) {
        int p = i >> 3, k = i & 7;
        float acc = 0.f;
        if (k < 5) {
            #pragma unroll
            for (int m4 = 0; m4 < 2; ++m4) acc += dot4(ldf4(&S01[p*12 + 4*m4]), ldf4(&A2T[k*12 + 4*m4]));
        }
        M2[p*12 + k] = acc;
    }
    __syncthreads();

    for (int i = t; i < 625; i += 256) {
        int p = i / 25, q = i - p*25;
        float acc = A0[p*28 + q];
        #pragma unroll
        for (int m4 = 0; m4 < 2; ++m4) acc += dot4(ldf4(&M2[p*12 + 4*m4]), ldf4(&S01[q*12 + 4*m4]));
        A0[p*28 + q] = acc;
    }
    __syncthreads();

    if (t < 25) {
        float4 r[7]; float mx = -1e30f;
        #pragma unroll
        for (int u = 0; u < 7; ++u) { r[u] = ldf4(&A0[t*28 + 4*u]); mx = fmaxf(mx, vmax4(r[u])); }
        float sm = 0.f;
        #pragma unroll
        for (int u = 0; u < 7; ++u) sm += vsum4(exp4(r[u], mx));
        sv[t] = mx; tv[t] = 1.f/sm;
    }
    __syncthreads();

    for (int i = t; i < 625; i += 256) {
        int p = i / 25, q = i - p*25;
        out[(size_t)g*625 + i] = __expf(A0[p*28 + q] - sv[p]) * tv[p];
    }
}

extern "C" void kernel_launch(void* const* d_in, const int* in_sizes, int n_in,
                              void* d_out, int out_size, void* d_ws, size_t ws_size,
                              hipStream_t stream) {
    const float* src = (const float*)d_in[0];
    const float* W   = (const float*)d_in[1];
    float* ws = (float*)d_ws;

    prep_kernel<<<16, 64, 0, stream>>>(W,
        (const float*)d_in[2],  (const float*)d_in[3],
        (const float*)d_in[6],  (const float*)d_in[7],
        (const float*)d_in[10], (const float*)d_in[11],
        (const float*)d_in[4],  (const float*)d_in[5],
        (const float*)d_in[8],  (const float*)d_in[9],
        (const float*)d_in[12], (const float*)d_in[13],
        (const float*)d_in[14], (const float*)d_in[16],
        (const float*)d_in[18], (const float*)d_in[20],
        ws);

    float* out = (float*)d_out;
    spatial_kernel<<<16384, 256, 0, stream>>>(
        src, ws, ws + 768, ws + 1536,
        (const float*)d_in[15], (const float*)d_in[17],
        out, 16384/8);
    temporal_kernel<<<6400, 512, 0, stream>>>(
        src, ws + 384,
        (const float*)d_in[18], (const float*)d_in[19],
        (const float*)d_in[20], (const float*)d_in[21],
        out + 10240000, 6400/8);
}

// Round 10
// 482.760 us; speedup vs baseline: 1.9892x; 1.0282x over previous
//
#include <hip/hip_runtime.h>
#include <math.h>

constexpr float LEAKY = 0.2f;

__device__ __forceinline__ float4 ldf4(const float* p){ return *reinterpret_cast<const float4*>(p); }
__device__ __forceinline__ void stf4(float* p, float4 v){ *reinterpret_cast<float4*>(p) = v; }
__device__ __forceinline__ float dot4(float4 a, float4 b){ return a.x*b.x + a.y*b.y + a.z*b.z + a.w*b.w; }
__device__ __forceinline__ float4 fma4(float s, float4 b, float4 acc){
    acc.x += s*b.x; acc.y += s*b.y; acc.z += s*b.z; acc.w += s*b.w; return acc;
}
__device__ __forceinline__ float lrelu(float f){ return f > 0.f ? f : LEAKY*f; }
__device__ __forceinline__ float4 lrelu4(float s, float4 t){
    float4 r; r.x = lrelu(s+t.x); r.y = lrelu(s+t.y); r.z = lrelu(s+t.z); r.w = lrelu(s+t.w); return r;
}
__device__ __forceinline__ float vmax4(float4 v){ return fmaxf(fmaxf(v.x,v.y), fmaxf(v.z,v.w)); }
__device__ __forceinline__ float vsum4(float4 v){ return v.x+v.y+v.z+v.w; }
__device__ __forceinline__ float4 exp4(float4 a, float mx){
    float4 r; r.x = __expf(a.x-mx); r.y = __expf(a.y-mx); r.z = __expf(a.z-mx); r.w = __expf(a.w-mx); return r;
}

// ws layout (floats): wv[12*64]@0 | WspT0[12*64]@768 | WspT1[5*64]@1536 | WtpT0[32*64]@1856 | WtpT1[16*64]@3904
__global__ void prep_kernel(const float* __restrict__ W,
    const float* a0, const float* a1, const float* a2,  const float* a3,
    const float* a4, const float* a5, const float* a6,  const float* a7,
    const float* a8, const float* a9, const float* a10, const float* a11,
    const float* __restrict__ Wsp0, const float* __restrict__ Wsp1,
    const float* __restrict__ Wtp0, const float* __restrict__ Wtp1,
    float* __restrict__ ws)
{
    int blk = blockIdx.x, t = threadIdx.x;
    if (blk < 12) {
        const float* as[12] = {a0,a1,a2,a3,a4,a5,a6,a7,a8,a9,a10,a11};
        const float* a = as[blk];
        float s = 0.f;
        #pragma unroll
        for (int h = 0; h < 128; ++h) s += W[t*128 + h] * a[h];
        ws[blk*64 + t] = s;
    } else if (blk == 12) {
        for (int i = t; i < 768; i += 64) { int k = i >> 6, c = i & 63; ws[768 + i] = Wsp0[c*12 + k]; }
    } else if (blk == 13) {
        for (int i = t; i < 320; i += 64) { int k = i >> 6, c = i & 63; ws[1536 + i] = Wsp1[c*5 + k]; }
    } else if (blk == 14) {
        for (int i = t; i < 2048; i += 64) { int k = i >> 6, c = i & 63; ws[1856 + i] = Wtp0[c*32 + k]; }
    } else {
        for (int i = t; i < 1024; i += 64) { int k = i >> 6, c = i & 63; ws[3904 + i] = Wtp1[c*16 + k]; }
    }
}

// ================== TEMPORAL: 6400 graphs of 64 nodes, 512 threads ==================
// R9 base (64 VGPR, 2 blocks/CU). R10: fusion factored as
//   fusion = A0 + S0 @ (A1 + S1@A2@S1^T) @ S0^T
// -> T1 = S1@A2 (A2 on the fly), B = A1 + T1@S1^T (in-place over A1),
//    then M1/fusion phases run verbatim; S01/M2/fusion2 deleted.
__global__ __launch_bounds__(512, 4)
void temporal_kernel(const float* __restrict__ src, const float* __restrict__ wvec_g,
                     const float* __restrict__ Wp0, const float* __restrict__ b0,
                     const float* __restrict__ Wp1, const float* __restrict__ b1,
                     float* __restrict__ out, int nwg8)
{
    constexpr int NT = 512;
    constexpr int oA1 = 0;          // [32][36]  A1 -> B (in place)
    constexpr int oP1 = 1152;       // [32][20]  P1T -> T1
    constexpr int oS1 = 1792;       // [32][20]

    __shared__ __align__(16) float xr[4352];   // x0[64][68]; tenants after x0 dies
    __shared__ __align__(16) float A0[4352];   // attn0 -> fusion (in place) [64][68]
    __shared__ __align__(16) float PR[2304];   // P0[64][36] -> x1[32][68] -> M1[64][36]
    __shared__ __align__(16) float S0[2304];   // [64][36]
    __shared__ __align__(16) float sv[64], tv[64], rx[64], rs[64];
    __shared__ __align__(16) float wv[384];

    const int tid = threadIdx.x;
    const int g = (blockIdx.x & 7) * nwg8 + (blockIdx.x >> 3);
    const int b = g / 25, inner = g - b*25;

    for (int i = tid; i < 384; i += NT) wv[i] = wvec_g[i];
    for (int i = tid; i < 4096; i += NT) {
        int c = i >> 6, r = i & 63;
        xr[r*68 + c] = src[((size_t)(b*64 + c)*64 + r)*25 + inner];
    }
    __syncthreads();

    // ---- phase 1: {s0,t0 | P0 = x0@Wp0} ----
    for (int i = tid; i < 128; i += NT) {
        int which = i >> 6, p = i & 63;
        const float* w = wv + which*64;
        float acc = 0.f;
        #pragma unroll
        for (int c = 0; c < 64; c += 4) acc += dot4(ldf4(&xr[p*68 + c]), ldf4(&w[c]));
        if (which) tv[p] = acc; else sv[p] = acc;
    }
    for (int i = tid; i < 512; i += NT) {
        int p = i >> 3, k4 = i & 7;
        float4 acc = {0,0,0,0};
        #pragma unroll
        for (int c = 0; c < 64; ++c) acc = fma4(xr[p*68 + c], ldf4(&Wp0[c*32 + 4*k4]), acc);
        stf4(&PR[p*36 + 4*k4], acc);
    }
    __syncthreads();

    // ---- phase 2: A0 = leaky(s+t^T) ----
    for (int i = tid; i < 1024; i += NT) {
        int p = i >> 4, q4 = i & 15;
        stf4(&A0[p*68 + 4*q4], lrelu4(sv[p], ldf4(&tv[4*q4])));
    }
    __syncthreads();

    // ---- phase 3: S0raw = A0 @ P0 + b0 (k8 tiles: 256 thr x 8 floats) ----
    if (tid < 256) {
        int p = tid >> 2, k8 = tid & 3;
        float4 acc0 = ldf4(&b0[8*k8]);
        float4 acc1 = ldf4(&b0[8*k8 + 4]);
        #pragma unroll
        for (int m = 0; m < 64; ++m) {
            float a = A0[p*68 + m];
            acc0 = fma4(a, ldf4(&PR[m*36 + 8*k8]), acc0);
            acc1 = fma4(a, ldf4(&PR[m*36 + 8*k8 + 4]), acc1);
        }
        stf4(&S0[p*36 + 8*k8], acc0);
        stf4(&S0[p*36 + 8*k8 + 4], acc1);
    }
    __syncthreads();

    // ---- phase 4: row softmax S0 (8 lanes/row, all 512 threads) ----
    {
        int p = tid >> 3, l = tid & 7;
        float4 v = ldf4(&S0[p*36 + 4*l]);
        float mx = vmax4(v);
        mx = fmaxf(mx, __shfl_xor(mx,1)); mx = fmaxf(mx, __shfl_xor(mx,2)); mx = fmaxf(mx, __shfl_xor(mx,4));
        v = exp4(v, mx);
        float sm = vsum4(v);
        sm += __shfl_xor(sm,1); sm += __shfl_xor(sm,2); sm += __shfl_xor(sm,4);
        float inv = 1.f/sm;
        v.x *= inv; v.y *= inv; v.z *= inv; v.w *= inv;
        stf4(&S0[p*36 + 4*l], v);
    }
    __syncthreads();

    // ---- phase 5: x1 = S0^T @ x0 (c8 tiles: 256 thr x 8 floats, into PR stride 68) ----
    if (tid < 256) {
        int k = tid >> 3, c8 = tid & 7;
        float4 acc0 = {0,0,0,0}, acc1 = {0,0,0,0};
        #pragma unroll
        for (int p = 0; p < 64; ++p) {
            float s = S0[p*36 + k];
            acc0 = fma4(s, ldf4(&xr[p*68 + 8*c8]), acc0);
            acc1 = fma4(s, ldf4(&xr[p*68 + 8*c8 + 4]), acc1);
        }
        stf4(&PR[k*68 + 8*c8], acc0);
        stf4(&PR[k*68 + 8*c8 + 4], acc1);
    }
    __syncthreads();

    // ---- phase 6: {s1,t1 | P1 = x1@Wp1} ----
    for (int i = tid; i < 64; i += NT) {
        int which = i >> 5, p = i & 31;
        const float* w = wv + (2 + which)*64;
        float acc = 0.f;
        #pragma unroll
        for (int c = 0; c < 64; c += 4) acc += dot4(ldf4(&PR[p*68 + c]), ldf4(&w[c]));
        if (which) tv[p] = acc; else sv[p] = acc;
    }
    for (int i = tid; i < 128; i += NT) {
        int p = i >> 2, k4 = i & 3;
        float4 acc = {0,0,0,0};
        #pragma unroll
        for (int c = 0; c < 64; ++c) acc = fma4(PR[p*68 + c], ldf4(&Wp1[c*16 + 4*k4]), acc);
        stf4(&xr[oP1 + p*20 + 4*k4], acc);
    }
    __syncthreads();

    // ---- phase 7: A1 ----
    for (int i = tid; i < 1024; i += NT) {
        int p = i >> 5, q = i & 31;
        xr[oA1 + p*36 + q] = lrelu(sv[p] + tv[q]);
    }
    __syncthreads();

    // ---- phase 8: S1raw = A1@P1 + b1 ----
    for (int i = tid; i < 128; i += NT) {
        int p = i >> 2, k4 = i & 3;
        float4 acc = ldf4(&b1[4*k4]);
        #pragma unroll
        for (int m = 0; m < 32; ++m) acc = fma4(xr[oA1 + p*36 + m], ldf4(&xr[oP1 + m*20 + 4*k4]), acc);
        stf4(&xr[oS1 + p*20 + 4*k4], acc);
    }
    __syncthreads();

    // ---- phase 9: {row softmax S1 (128 thr, 4 lanes/row) | u,v dots (thr 128..191)} ----
    if (tid < 128) {
        int m = tid >> 2, l = tid & 3;
        float4 v = ldf4(&xr[oS1 + m*20 + 4*l]);
        float mx = vmax4(v);
        mx = fmaxf(mx, __shfl_xor(mx,1)); mx = fmaxf(mx, __shfl_xor(mx,2));
        v = exp4(v, mx);
        float sm = vsum4(v);
        sm += __shfl_xor(sm,1); sm += __shfl_xor(sm,2);
        float inv = 1.f/sm;
        v.x *= inv; v.y *= inv; v.z *= inv; v.w *= inv;
        stf4(&xr[oS1 + m*20 + 4*l], v);
    } else if (tid < 192) {
        int i = tid - 128;
        int which = i >> 5, p = i & 31;
        const float* w = wv + (4 + which)*64;
        float acc = 0.f;
        #pragma unroll
        for (int c = 0; c < 64; c += 4) acc += dot4(ldf4(&PR[p*68 + c]), ldf4(&w[c]));
        if (which) tv[p] = acc; else sv[p] = acc;
    }
    __syncthreads();

    // ---- phase 10: rx/rs = S1^T . (u,v) ----
    for (int k = tid; k < 16; k += NT) {
        float a = 0.f, c2 = 0.f;
        #pragma unroll
        for (int n = 0; n < 32; ++n) { float s1 = xr[oS1 + n*20 + k]; a += s1*sv[n]; c2 += s1*tv[n]; }
        rx[k] = a; rs[k] = c2;
    }
    __syncthreads();

    // ---- phase 11: T1 = S1 @ A2 (A2 = lrelu(rx + rs^T) on the fly), into oP1 ----
    {
        int m = tid >> 4, k = tid & 15;
        float rsk = rs[k];
        float acc = 0.f;
        #pragma unroll
        for (int j = 0; j < 16; ++j)
            acc += xr[oS1 + m*20 + j] * lrelu(rx[j] + rsk);
        xr[oP1 + m*20 + k] = acc;
    }
    __syncthreads();

    // ---- phase 11b: B = A1 + T1@S1^T, in place over A1 (element-owner RMW) ----
    for (int i = tid; i < 1024; i += NT) {
        int m = i >> 5, n = i & 31;
        float acc = xr[oA1 + m*36 + n];
        #pragma unroll
        for (int j4 = 0; j4 < 4; ++j4)
            acc += dot4(ldf4(&xr[oP1 + m*20 + 4*j4]), ldf4(&xr[oS1 + n*20 + 4*j4]));
        xr[oA1 + m*36 + n] = acc;
    }
    __syncthreads();

    // ---- phase 11c: M1 = S0 @ B (into PR) — verbatim old M1, reads oA1 (now B) ----
    for (int i = tid; i < 512; i += NT) {
        int p = i >> 3, k4 = i & 7;
        float4 acc = {0,0,0,0};
        #pragma unroll
        for (int m = 0; m < 32; ++m) acc = fma4(S0[p*36 + m], ldf4(&xr[oA1 + m*36 + 4*k4]), acc);
        stf4(&PR[p*36 + 4*k4], acc);
    }
    __syncthreads();

    // ---- phase 12: fusion += M1@S0^T ----
    {
        int q = tid & 63, pg = tid >> 6;
        float4 s0r[8];
        #pragma unroll
        for (int j = 0; j < 8; ++j) s0r[j] = ldf4(&S0[q*36 + 4*j]);
        #pragma unroll
        for (int pi = 0; pi < 8; ++pi) {
            int p = pg*8 + pi;
            float acc = 0.f;
            #pragma unroll
            for (int j = 0; j < 8; ++j) acc += dot4(ldf4(&PR[p*36 + 4*j]), s0r[j]);
            A0[p*68 + q] += acc;
        }
    }
    __syncthreads();

    // ---- phase 15+16 fused: row softmax of fusion + write (8 lanes/row, 512 thr) ----
    {
        int p = tid >> 3, l = tid & 7;
        float4 v1 = ldf4(&A0[p*68 + 4*l]);
        float4 v2 = ldf4(&A0[p*68 + 32 + 4*l]);
        float mx = fmaxf(vmax4(v1), vmax4(v2));
        mx = fmaxf(mx, __shfl_xor(mx,1)); mx = fmaxf(mx, __shfl_xor(mx,2)); mx = fmaxf(mx, __shfl_xor(mx,4));
        float4 e1 = exp4(v1, mx), e2 = exp4(v2, mx);
        float sm = vsum4(e1) + vsum4(e2);
        sm += __shfl_xor(sm,1); sm += __shfl_xor(sm,2); sm += __shfl_xor(sm,4);
        float inv = 1.f/sm;
        e1.x*=inv; e1.y*=inv; e1.z*=inv; e1.w*=inv;
        e2.x*=inv; e2.y*=inv; e2.z*=inv; e2.w*=inv;
        size_t base = (size_t)g*4096 + (size_t)p*64;
        stf4(&out[base + 4*l], e1);
        stf4(&out[base + 32 + 4*l], e2);
    }
}

// ================== SPATIAL: 16384 graphs of 25 nodes, 256 threads ==================
__global__ __launch_bounds__(256, 4)
void spatial_kernel(const float* __restrict__ src, const float* __restrict__ wvg,
                    const float* __restrict__ WpT0, const float* __restrict__ WpT1,
                    const float* __restrict__ b0, const float* __restrict__ b1,
                    float* __restrict__ out, int nwg8)
{
    __shared__ __align__(16) float Rx0[1700];
    __shared__ __align__(16) float RA0[700];
    __shared__ __align__(16) float RPR[816];
    __shared__ __align__(16) float RS0[500];
    __shared__ __align__(16) float sv[32], tv[32], ua[32], va[32], rxa[8], rsa[8];

    float* x0  = Rx0;
    float* A1  = Rx0;
    float* A1T = Rx0 + 240;
    float* P1T = Rx0 + 480;
    float* S1  = Rx0 + 540;
    float* S1T = Rx0 + 684;
    float* A2T = Rx0 + 744;
    float* S01 = Rx0 + 804;
    float* A0  = RA0;
    float* P0T = RPR;
    float* x1  = RPR;
    float* M1  = RPR;
    float* M2  = RPR;
    float* S0  = RS0;

    const int t = threadIdx.x;
    const int g = (blockIdx.x & 7) * nwg8 + (blockIdx.x >> 3);
    const int b = g >> 6, inner = g & 63;
    const float* srcb = src + (size_t)b*102400 + inner*25;

    for (int i = t; i < 400; i += 256) {
        int r = i % 25, c0 = (i / 25) << 2;
        float4 v;
        v.x = srcb[(c0+0)*1600 + r];
        v.y = srcb[(c0+1)*1600 + r];
        v.z = srcb[(c0+2)*1600 + r];
        v.w = srcb[(c0+3)*1600 + r];
        stf4(&x0[r*68 + c0], v);
    }
    __syncthreads();

    if (t < 50) {
        int which = t / 25, p = t - which*25;
        const float* w = wvg + which*64;
        float a = 0.f;
        #pragma unroll
        for (int c4 = 0; c4 < 16; ++c4) a += dot4(ldf4(&x0[p*68 + 4*c4]), ldf4(&w[4*c4]));
        if (which) tv[p] = a; else sv[p] = a;
    }
    for (int i = t; i < 336; i += 256) {
        int k = i / 28, m = i - k*28;
        float a = 0.f;
        if (m < 25) {
            #pragma unroll
            for (int c4 = 0; c4 < 16; ++c4) a += dot4(ldf4(&WpT0[k*64 + 4*c4]), ldf4(&x0[m*68 + 4*c4]));
        }
        P0T[k*28 + m] = a;
    }
    __syncthreads();

    for (int i = t; i < 700; i += 256) {
        int p = i / 28, q = i - p*28;
        A0[i] = (q < 25) ? lrelu(sv[p] + tv[q]) : -1e30f;
    }
    __syncthreads();

    for (int i = t; i < 300; i += 256) {
        int p = i / 12, k = i - p*12;
        float acc = b0[k];
        #pragma unroll
        for (int m4 = 0; m4 < 7; ++m4) acc += dot4(ldf4(&A0[p*28 + 4*m4]), ldf4(&P0T[k*28 + 4*m4]));
        S0[p*20 + k] = acc;
    }
    __syncthreads();

    if (t < 25) {
        float4 r[3]; float mx = -1e30f;
        #pragma unroll
        for (int u = 0; u < 3; ++u) { r[u] = ldf4(&S0[t*20 + 4*u]); mx = fmaxf(mx, vmax4(r[u])); }
        float sm = 0.f;
        #pragma unroll
        for (int u = 0; u < 3; ++u) { r[u] = exp4(r[u], mx); sm += vsum4(r[u]); }
        float inv = 1.f/sm;
        #pragma unroll
        for (int u = 0; u < 3; ++u) {
            r[u].x *= inv; r[u].y *= inv; r[u].z *= inv; r[u].w *= inv;
            stf4(&S0[t*20 + 4*u], r[u]);
        }
    }
    __syncthreads();

    if (t < 96) {
        int k = t >> 3, c0 = (t & 7) << 3;
        float4 a = {0,0,0,0}, bb = {0,0,0,0};
        #pragma unroll
        for (int p = 0; p < 25; ++p) {
            float s = S0[p*20 + k];
            a  = fma4(s, ldf4(&x0[p*68 + c0]), a);
            bb = fma4(s, ldf4(&x0[p*68 + c0 + 4]), bb);
        }
        stf4(&x1[k*68 + c0], a);
        stf4(&x1[k*68 + c0 + 4], bb);
    }
    __syncthreads();

    if (t < 48) {
        int which = t / 12, p = t - which*12;
        const float* w = wvg + (2+which)*64;
        float a = 0.f;
        #pragma unroll
        for (int c4 = 0; c4 < 16; ++c4) a += dot4(ldf4(&x1[p*68 + 4*c4]), ldf4(&w[4*c4]));
        if (which == 0) sv[p] = a; else if (which == 1) tv[p] = a;
        else if (which == 2) ua[p] = a; else va[p] = a;
    }
    for (int i = t; i < 60; i += 256) {
        int j = i / 12, k = i - j*12;
        float a = 0.f;
        #pragma unroll
        for (int c4 = 0; c4 < 16; ++c4) a += dot4(ldf4(&WpT1[j*64 + 4*c4]), ldf4(&x1[k*68 + 4*c4]));
        P1T[j*12 + k] = a;
    }
    __syncthreads();

    for (int i = t; i < 288; i += 256) {
        int mat = i / 144, rr = (i - mat*144) / 12, q = i % 12;
        if (mat == 0) A1 [rr*20 + q] = lrelu(sv[rr] + tv[q]);
        else          A1T[rr*20 + q] = lrelu(sv[q] + tv[rr]);
    }
    __syncthreads();

    for (int i = t; i < 300; i += 256) {
        int p = i / 12, k = i - p*12;
        float acc = 0.f;
        #pragma unroll
        for (int m4 = 0; m4 < 3; ++m4) acc += dot4(ldf4(&S0[p*20 + 4*m4]), ldf4(&A1T[k*20 + 4*m4]));
        M1[p*20 + k] = acc;
    }
    for (int i = t; i < 60; i += 256) {
        int m = i / 5, j = i - m*5;
        float acc = b1[j];
        #pragma unroll
        for (int k4 = 0; k4 < 3; ++k4) acc += dot4(ldf4(&A1[m*20 + 4*k4]), ldf4(&P1T[j*12 + 4*k4]));
        S1[m*12 + j] = acc;
    }
    __syncthreads();

    if (t < 12) {
        float mx = -1e30f;
        float r0 = S1[t*12+0], r1 = S1[t*12+1], r2 = S1[t*12+2], r3 = S1[t*12+3], r4 = S1[t*12+4];
        mx = fmaxf(fmaxf(fmaxf(r0,r1), fmaxf(r2,r3)), r4);
        r0 = __expf(r0-mx); r1 = __expf(r1-mx); r2 = __expf(r2-mx); r3 = __expf(r3-mx); r4 = __expf(r4-mx);
        float inv = 1.f/(r0+r1+r2+r3+r4);
        S1[t*12+0] = r0*inv; S1[t*12+1] = r1*inv; S1[t*12+2] = r2*inv; S1[t*12+3] = r3*inv; S1[t*12+4] = r4*inv;
    }
    for (int i = t; i < 625; i += 256) {
        int p = i / 25, q = i - p*25;
        float acc = A0[p*28 + q];
        #pragma unroll
        for (int m4 = 0; m4 < 3; ++m4) acc += dot4(ldf4(&M1[p*20 + 4*m4]), ldf4(&S0[q*20 + 4*m4]));
        A0[p*28 + q] = acc;
    }
    __syncthreads();

    for (int i = t; i < 60; i += 256) {
        int j = i / 12, m = i - j*12;
        S1T[j*12 + m] = S1[m*12 + j];
    }
    if (t >= 64 && t < 74) {
        int tp = t - 64, which = tp / 5, k = tp - which*5;
        float a = 0.f;
        #pragma unroll
        for (int n = 0; n < 12; ++n) a += S1[n*12 + k] * (which ? va[n] : ua[n]);
        if (which) rsa[k] = a; else rxa[k] = a;
    }
    __syncthreads();

    for (int i = t; i < 40; i += 256) {
        int q = i >> 3, p = i & 7;
        A2T[q*12 + p] = (p < 5) ? lrelu(rxa[p] + rsa[q]) : 0.f;
    }
    for (int i = t; i < 200; i += 256) {
        int p = i >> 3, c = i & 7;
        float acc = 0.f;
        if (c < 5) {
            #pragma unroll
            for (int m4 = 0; m4 < 3; ++m4) acc += dot4(ldf4(&S0[p*20 + 4*m4]), ldf4(&S1T[c*12 + 4*m4]));
        }
        S01[p*12 + c] = acc;
    }
    __syncthreads();

    for (int i = t; i < 200; i += 256) {
        int p = i >> 3, k = i & 7;
        float acc = 0.f;
        if (k < 5) {
            #pragma unroll
            for (int m4 = 0; m4 < 2; ++m4) acc += dot4(ldf4(&S01[p*12 + 4*m4]), ldf4(&A2T[k*12 + 4*m4]));
        }
        M2[p*12 + k] = acc;
    }
    __syncthreads();

    for (int i = t; i < 625; i += 256) {
        int p = i / 25, q = i - p*25;
        float acc = A0[p*28 + q];
        #pragma unroll
        for (int m4 = 0; m4 < 2; ++m4) acc += dot4(ldf4(&M2[p*12 + 4*m4]), ldf4(&S01[q*12 + 4*m4]));
        A0[p*28 + q] = acc;
    }
    __syncthreads();

    if (t < 25) {
        float4 r[7]; float mx = -1e30f;
        #pragma unroll
        for (int u = 0; u < 7; ++u) { r[u] = ldf4(&A0[t*28 + 4*u]); mx = fmaxf(mx, vmax4(r[u])); }
        float sm = 0.f;
        #pragma unroll
        for (int u = 0; u < 7; ++u) sm += vsum4(exp4(r[u], mx));
        sv[t] = mx; tv[t] = 1.f/sm;
    }
    __syncthreads();

    for (int i = t; i < 625; i += 256) {
        int p = i / 25, q = i - p*25;
        out[(size_t)g*625 + i] = __expf(A0[p*28 + q] - sv[p]) * tv[p];
    }
}

extern "C" void kernel_launch(void* const* d_in, const int* in_sizes, int n_in,
                              void* d_out, int out_size, void* d_ws, size_t ws_size,
                              hipStream_t stream) {
    const float* src = (const float*)d_in[0];
    const float* W   = (const float*)d_in[1];
    float* ws = (float*)d_ws;

    prep_kernel<<<16, 64, 0, stream>>>(W,
        (const float*)d_in[2],  (const float*)d_in[3],
        (const float*)d_in[6],  (const float*)d_in[7],
        (const float*)d_in[10], (const float*)d_in[11],
        (const float*)d_in[4],  (const float*)d_in[5],
        (const float*)d_in[8],  (const float*)d_in[9],
        (const float*)d_in[12], (const float*)d_in[13],
        (const float*)d_in[14], (const float*)d_in[16],
        (const float*)d_in[18], (const float*)d_in[20],
        ws);

    float* out = (float*)d_out;
    spatial_kernel<<<16384, 256, 0, stream>>>(
        src, ws, ws + 768, ws + 1536,
        (const float*)d_in[15], (const float*)d_in[17],
        out, 16384/8);
    temporal_kernel<<<6400, 512, 0, stream>>>(
        src, ws + 384,
        (const float*)d_in[18], (const float*)d_in[19],
        (const float*)d_in[20], (const float*)d_in[21],
        out + 10240000, 6400/8);
}

// Round 11
// 438.919 us; speedup vs baseline: 2.1879x; 1.0999x over previous
//
#include <hip/hip_runtime.h>
#include <math.h>

constexpr float LEAKY = 0.2f;

__device__ __forceinline__ float4 ldf4(const float* p){ return *reinterpret_cast<const float4*>(p); }
__device__ __forceinline__ void stf4(float* p, float4 v){ *reinterpret_cast<float4*>(p) = v; }
__device__ __forceinline__ float dot4(float4 a, float4 b){ return a.x*b.x + a.y*b.y + a.z*b.z + a.w*b.w; }
__device__ __forceinline__ float4 fma4(float s, float4 b, float4 acc){
    acc.x += s*b.x; acc.y += s*b.y; acc.z += s*b.z; acc.w += s*b.w; return acc;
}
__device__ __forceinline__ float lrelu(float f){ return f > 0.f ? f : LEAKY*f; }
__device__ __forceinline__ float4 lrelu4(float s, float4 t){
    float4 r; r.x = lrelu(s+t.x); r.y = lrelu(s+t.y); r.z = lrelu(s+t.z); r.w = lrelu(s+t.w); return r;
}
__device__ __forceinline__ float vmax4(float4 v){ return fmaxf(fmaxf(v.x,v.y), fmaxf(v.z,v.w)); }
__device__ __forceinline__ float vsum4(float4 v){ return v.x+v.y+v.z+v.w; }
__device__ __forceinline__ float4 exp4(float4 a, float mx){
    float4 r; r.x = __expf(a.x-mx); r.y = __expf(a.y-mx); r.z = __expf(a.z-mx); r.w = __expf(a.w-mx); return r;
}

// ws layout (floats): wv[12*64]@0 | WspT0[12*64]@768 | WspT1[5*64]@1536 | WtpT0[32*64]@1856 | WtpT1[16*64]@3904
__global__ void prep_kernel(const float* __restrict__ W,
    const float* a0, const float* a1, const float* a2,  const float* a3,
    const float* a4, const float* a5, const float* a6,  const float* a7,
    const float* a8, const float* a9, const float* a10, const float* a11,
    const float* __restrict__ Wsp0, const float* __restrict__ Wsp1,
    const float* __restrict__ Wtp0, const float* __restrict__ Wtp1,
    float* __restrict__ ws)
{
    int blk = blockIdx.x, t = threadIdx.x;
    if (blk < 12) {
        const float* as[12] = {a0,a1,a2,a3,a4,a5,a6,a7,a8,a9,a10,a11};
        const float* a = as[blk];
        float s = 0.f;
        #pragma unroll
        for (int h = 0; h < 128; ++h) s += W[t*128 + h] * a[h];
        ws[blk*64 + t] = s;
    } else if (blk == 12) {
        for (int i = t; i < 768; i += 64) { int k = i >> 6, c = i & 63; ws[768 + i] = Wsp0[c*12 + k]; }
    } else if (blk == 13) {
        for (int i = t; i < 320; i += 64) { int k = i >> 6, c = i & 63; ws[1536 + i] = Wsp1[c*5 + k]; }
    } else if (blk == 14) {
        for (int i = t; i < 2048; i += 64) { int k = i >> 6, c = i & 63; ws[1856 + i] = Wtp0[c*32 + k]; }
    } else {
        for (int i = t; i < 1024; i += 64) { int k = i >> 6, c = i & 63; ws[3904 + i] = Wtp1[c*16 + k]; }
    }
}

// ================== TEMPORAL: 6400 graphs of 64 nodes, 512 threads ==================
// R10 base + R11: x1 eliminated (P1 = S0^T@(x0@Wp1), s1/t1/u/v = S0^T@(x0.w));
// b128 row reads in phases 1/3; phase 3 retiled 2p x 8k.
__global__ __launch_bounds__(512, 4)
void temporal_kernel(const float* __restrict__ src, const float* __restrict__ wvec_g,
                     const float* __restrict__ Wp0, const float* __restrict__ b0,
                     const float* __restrict__ Wp1, const float* __restrict__ b1,
                     float* __restrict__ out, int nwg8)
{
    constexpr int NT = 512;
    constexpr int oA1 = 0;          // [32][36]  A1 -> B (in place)
    constexpr int oP1 = 1152;       // [32][20]  P1 -> T1
    constexpr int oS1 = 1792;       // [32][20]

    __shared__ __align__(16) float xr[4352];   // x0[64][68]; dead after PH1; tenants oA1/oP1/oS1
    __shared__ __align__(16) float A0[4352];   // attn0 -> fusion (in place) [64][68]
    __shared__ __align__(16) float PR[2304];   // P0[64][36] -> M1[64][36]
    __shared__ __align__(16) float S0[2304];   // [64][36]
    __shared__ __align__(16) float P01[1280];  // x0@Wp1 [64][20]
    __shared__ __align__(16) float dv[256];    // 4 x [64] dots of x0 with ws1,wd1,ws2,wd2
    __shared__ __align__(16) float sv[64], tv[64], rx[64], rs[64];
    __shared__ __align__(16) float ua[32], va[32];
    __shared__ __align__(16) float wv[384];

    const int tid = threadIdx.x;
    const int g = (blockIdx.x & 7) * nwg8 + (blockIdx.x >> 3);
    const int b = g / 25, inner = g - b*25;

    for (int i = tid; i < 384; i += NT) wv[i] = wvec_g[i];
    for (int i = tid; i < 4096; i += NT) {
        int c = i >> 6, r = i & 63;
        xr[r*68 + c] = src[((size_t)(b*64 + c)*64 + r)*25 + inner];
    }
    __syncthreads();

    // ---- PH1: {6 dots per x0 row | P0 = x0@Wp0 | P01 = x0@Wp1} ----
    for (int i = tid; i < 384; i += NT) {
        int which = i >> 6, p = i & 63;
        const float* w = wv + which*64;
        float acc = 0.f;
        #pragma unroll
        for (int c4 = 0; c4 < 16; ++c4) acc += dot4(ldf4(&xr[p*68 + 4*c4]), ldf4(&w[4*c4]));
        if (which == 0) sv[p] = acc;
        else if (which == 1) tv[p] = acc;
        else dv[(which-2)*64 + p] = acc;
    }
    for (int i = tid; i < 512; i += NT) {
        int p = i >> 3, k4 = i & 7;
        float4 acc = {0,0,0,0};
        #pragma unroll
        for (int c4 = 0; c4 < 16; ++c4) {
            float4 xv = ldf4(&xr[p*68 + 4*c4]);
            acc = fma4(xv.x, ldf4(&Wp0[(4*c4+0)*32 + 4*k4]), acc);
            acc = fma4(xv.y, ldf4(&Wp0[(4*c4+1)*32 + 4*k4]), acc);
            acc = fma4(xv.z, ldf4(&Wp0[(4*c4+2)*32 + 4*k4]), acc);
            acc = fma4(xv.w, ldf4(&Wp0[(4*c4+3)*32 + 4*k4]), acc);
        }
        stf4(&PR[p*36 + 4*k4], acc);
    }
    for (int i = tid; i < 256; i += NT) {
        int p = i >> 2, k4 = i & 3;
        float4 acc = {0,0,0,0};
        #pragma unroll
        for (int c4 = 0; c4 < 16; ++c4) {
            float4 xv = ldf4(&xr[p*68 + 4*c4]);
            acc = fma4(xv.x, ldf4(&Wp1[(4*c4+0)*16 + 4*k4]), acc);
            acc = fma4(xv.y, ldf4(&Wp1[(4*c4+1)*16 + 4*k4]), acc);
            acc = fma4(xv.z, ldf4(&Wp1[(4*c4+2)*16 + 4*k4]), acc);
            acc = fma4(xv.w, ldf4(&Wp1[(4*c4+3)*16 + 4*k4]), acc);
        }
        stf4(&P01[p*20 + 4*k4], acc);
    }
    __syncthreads();

    // ---- PH2: A0 = lrelu(s + t^T) ----
    for (int i = tid; i < 1024; i += NT) {
        int p = i >> 4, q4 = i & 15;
        stf4(&A0[p*68 + 4*q4], lrelu4(sv[p], ldf4(&tv[4*q4])));
    }
    __syncthreads();

    // ---- PH3: S0raw = A0 @ P0 + b0 (2p x 8k tiles, 128 thr, b128 A0 reads) ----
    if (tid < 128) {
        int p0 = tid >> 2, k8 = tid & 3;
        float4 a00 = ldf4(&b0[8*k8]), a01 = ldf4(&b0[8*k8 + 4]);
        float4 a10 = a00, a11 = a01;
        #pragma unroll
        for (int m4 = 0; m4 < 16; ++m4) {
            float4 av0 = ldf4(&A0[p0*68 + 4*m4]);
            float4 av1 = ldf4(&A0[(p0+32)*68 + 4*m4]);
            const float* f0 = (const float*)&av0;
            const float* f1 = (const float*)&av1;
            #pragma unroll
            for (int j = 0; j < 4; ++j) {
                float4 pr0 = ldf4(&PR[(4*m4+j)*36 + 8*k8]);
                float4 pr1 = ldf4(&PR[(4*m4+j)*36 + 8*k8 + 4]);
                a00 = fma4(f0[j], pr0, a00); a01 = fma4(f0[j], pr1, a01);
                a10 = fma4(f1[j], pr0, a10); a11 = fma4(f1[j], pr1, a11);
            }
        }
        stf4(&S0[p0*36 + 8*k8], a00);      stf4(&S0[p0*36 + 8*k8 + 4], a01);
        stf4(&S0[(p0+32)*36 + 8*k8], a10); stf4(&S0[(p0+32)*36 + 8*k8 + 4], a11);
    }
    __syncthreads();

    // ---- PH4: row softmax S0 (8 lanes/row, all 512 threads) ----
    {
        int p = tid >> 3, l = tid & 7;
        float4 v = ldf4(&S0[p*36 + 4*l]);
        float mx = vmax4(v);
        mx = fmaxf(mx, __shfl_xor(mx,1)); mx = fmaxf(mx, __shfl_xor(mx,2)); mx = fmaxf(mx, __shfl_xor(mx,4));
        v = exp4(v, mx);
        float sm = vsum4(v);
        sm += __shfl_xor(sm,1); sm += __shfl_xor(sm,2); sm += __shfl_xor(sm,4);
        float inv = 1.f/sm;
        v.x *= inv; v.y *= inv; v.z *= inv; v.w *= inv;
        stf4(&S0[p*36 + 4*l], v);
    }
    __syncthreads();

    // ---- PH5: {P1 = S0^T@P01 (128 thr) | s1/t1/u/v = S0^T . dv (thr 128..255)} ----
    if (tid < 128) {
        int k = tid >> 2, j4 = tid & 3;
        float4 acc = {0,0,0,0};
        #pragma unroll
        for (int p = 0; p < 64; ++p)
            acc = fma4(S0[p*36 + k], ldf4(&P01[p*20 + 4*j4]), acc);
        stf4(&xr[oP1 + k*20 + 4*j4], acc);
    } else if (tid < 256) {
        int i = tid - 128;
        int j = i >> 5, k = i & 31;
        const float* d = dv + j*64;
        float acc = 0.f;
        #pragma unroll
        for (int p = 0; p < 64; ++p) acc += S0[p*36 + k] * d[p];
        if (j == 0) sv[k] = acc; else if (j == 1) tv[k] = acc;
        else if (j == 2) ua[k] = acc; else va[k] = acc;
    }
    __syncthreads();

    // ---- PH7: A1 = lrelu(s1 + t1^T) ----
    for (int i = tid; i < 1024; i += NT) {
        int p = i >> 5, q = i & 31;
        xr[oA1 + p*36 + q] = lrelu(sv[p] + tv[q]);
    }
    __syncthreads();

    // ---- PH8: S1raw = A1@P1 + b1 ----
    for (int i = tid; i < 128; i += NT) {
        int p = i >> 2, k4 = i & 3;
        float4 acc = ldf4(&b1[4*k4]);
        #pragma unroll
        for (int m = 0; m < 32; ++m) acc = fma4(xr[oA1 + p*36 + m], ldf4(&xr[oP1 + m*20 + 4*k4]), acc);
        stf4(&xr[oS1 + p*20 + 4*k4], acc);
    }
    __syncthreads();

    // ---- PH9: row softmax S1 (128 thr, 4 lanes/row) ----
    if (tid < 128) {
        int m = tid >> 2, l = tid & 3;
        float4 v = ldf4(&xr[oS1 + m*20 + 4*l]);
        float mx = vmax4(v);
        mx = fmaxf(mx, __shfl_xor(mx,1)); mx = fmaxf(mx, __shfl_xor(mx,2));
        v = exp4(v, mx);
        float sm = vsum4(v);
        sm += __shfl_xor(sm,1); sm += __shfl_xor(sm,2);
        float inv = 1.f/sm;
        v.x *= inv; v.y *= inv; v.z *= inv; v.w *= inv;
        stf4(&xr[oS1 + m*20 + 4*l], v);
    }
    __syncthreads();

    // ---- PH10: rx/rs = S1^T . (u,v) ----
    for (int k = tid; k < 16; k += NT) {
        float a = 0.f, c2 = 0.f;
        #pragma unroll
        for (int n = 0; n < 32; ++n) { float s1 = xr[oS1 + n*20 + k]; a += s1*ua[n]; c2 += s1*va[n]; }
        rx[k] = a; rs[k] = c2;
    }
    __syncthreads();

    // ---- PH11: T1 = S1 @ A2 (A2 = lrelu(rx + rs^T) on the fly), into oP1 ----
    {
        int m = tid >> 4, k = tid & 15;
        float rsk = rs[k];
        float acc = 0.f;
        #pragma unroll
        for (int j = 0; j < 16; ++j)
            acc += xr[oS1 + m*20 + j] * lrelu(rx[j] + rsk);
        xr[oP1 + m*20 + k] = acc;
    }
    __syncthreads();

    // ---- PH11b: B = A1 + T1@S1^T, in place over A1 ----
    for (int i = tid; i < 1024; i += NT) {
        int m = i >> 5, n = i & 31;
        float acc = xr[oA1 + m*36 + n];
        #pragma unroll
        for (int j4 = 0; j4 < 4; ++j4)
            acc += dot4(ldf4(&xr[oP1 + m*20 + 4*j4]), ldf4(&xr[oS1 + n*20 + 4*j4]));
        xr[oA1 + m*36 + n] = acc;
    }
    __syncthreads();

    // ---- PH11c: M1 = S0 @ B (into PR) ----
    for (int i = tid; i < 512; i += NT) {
        int p = i >> 3, k4 = i & 7;
        float4 acc = {0,0,0,0};
        #pragma unroll
        for (int m = 0; m < 32; ++m) acc = fma4(S0[p*36 + m], ldf4(&xr[oA1 + m*36 + 4*k4]), acc);
        stf4(&PR[p*36 + 4*k4], acc);
    }
    __syncthreads();

    // ---- PH12: fusion += M1@S0^T ----
    {
        int q = tid & 63, pg = tid >> 6;
        float4 s0r[8];
        #pragma unroll
        for (int j = 0; j < 8; ++j) s0r[j] = ldf4(&S0[q*36 + 4*j]);
        #pragma unroll
        for (int pi = 0; pi < 8; ++pi) {
            int p = pg*8 + pi;
            float acc = 0.f;
            #pragma unroll
            for (int j = 0; j < 8; ++j) acc += dot4(ldf4(&PR[p*36 + 4*j]), s0r[j]);
            A0[p*68 + q] += acc;
        }
    }
    __syncthreads();

    // ---- epilogue: row softmax of fusion + write (8 lanes/row, 512 thr) ----
    {
        int p = tid >> 3, l = tid & 7;
        float4 v1 = ldf4(&A0[p*68 + 4*l]);
        float4 v2 = ldf4(&A0[p*68 + 32 + 4*l]);
        float mx = fmaxf(vmax4(v1), vmax4(v2));
        mx = fmaxf(mx, __shfl_xor(mx,1)); mx = fmaxf(mx, __shfl_xor(mx,2)); mx = fmaxf(mx, __shfl_xor(mx,4));
        float4 e1 = exp4(v1, mx), e2 = exp4(v2, mx);
        float sm = vsum4(e1) + vsum4(e2);
        sm += __shfl_xor(sm,1); sm += __shfl_xor(sm,2); sm += __shfl_xor(sm,4);
        float inv = 1.f/sm;
        e1.x*=inv; e1.y*=inv; e1.z*=inv; e1.w*=inv;
        e2.x*=inv; e2.y*=inv; e2.z*=inv; e2.w*=inv;
        size_t base = (size_t)g*4096 + (size_t)p*64;
        stf4(&out[base + 4*l], e1);
        stf4(&out[base + 32 + 4*l], e2);
    }
}

// ================== SPATIAL: 16384 graphs of 25 nodes, 256 threads ==================
// R11: fusion factored (B = A1 + (S1@A2)@S1^T in place, BT alongside);
// S1T/S01/M2/fusion-pass-2 deleted.
__global__ __launch_bounds__(256, 4)
void spatial_kernel(const float* __restrict__ src, const float* __restrict__ wvg,
                    const float* __restrict__ WpT0, const float* __restrict__ WpT1,
                    const float* __restrict__ b0, const float* __restrict__ b1,
                    float* __restrict__ out, int nwg8)
{
    __shared__ __align__(16) float Rx0[1700];
    __shared__ __align__(16) float RA0[700];
    __shared__ __align__(16) float RPR[816];
    __shared__ __align__(16) float RS0[500];
    __shared__ __align__(16) float sv[32], tv[32], ua[32], va[32], rxa[8], rsa[8];

    float* x0  = Rx0;
    float* A1  = Rx0;          // [12][20] -> B (in place)
    float* A1T = Rx0 + 240;    // [12][20] -> BT (in place)
    float* P1T = Rx0 + 480;    // [5][12]
    float* S1  = Rx0 + 540;    // [12][12]
    float* T1  = Rx0 + 744;    // [12][5]
    float* A0  = RA0;
    float* P0T = RPR;
    float* x1  = RPR;
    float* M1  = RPR;
    float* S0  = RS0;

    const int t = threadIdx.x;
    const int g = (blockIdx.x & 7) * nwg8 + (blockIdx.x >> 3);
    const int b = g >> 6, inner = g & 63;
    const float* srcb = src + (size_t)b*102400 + inner*25;

    for (int i = t; i < 400; i += 256) {
        int r = i % 25, c0 = (i / 25) << 2;
        float4 v;
        v.x = srcb[(c0+0)*1600 + r];
        v.y = srcb[(c0+1)*1600 + r];
        v.z = srcb[(c0+2)*1600 + r];
        v.w = srcb[(c0+3)*1600 + r];
        stf4(&x0[r*68 + c0], v);
    }
    __syncthreads();

    if (t < 50) {
        int which = t / 25, p = t - which*25;
        const float* w = wvg + which*64;
        float a = 0.f;
        #pragma unroll
        for (int c4 = 0; c4 < 16; ++c4) a += dot4(ldf4(&x0[p*68 + 4*c4]), ldf4(&w[4*c4]));
        if (which) tv[p] = a; else sv[p] = a;
    }
    for (int i = t; i < 336; i += 256) {
        int k = i / 28, m = i - k*28;
        float a = 0.f;
        if (m < 25) {
            #pragma unroll
            for (int c4 = 0; c4 < 16; ++c4) a += dot4(ldf4(&WpT0[k*64 + 4*c4]), ldf4(&x0[m*68 + 4*c4]));
        }
        P0T[k*28 + m] = a;
    }
    __syncthreads();

    for (int i = t; i < 700; i += 256) {
        int p = i / 28, q = i - p*28;
        A0[i] = (q < 25) ? lrelu(sv[p] + tv[q]) : -1e30f;
    }
    __syncthreads();

    for (int i = t; i < 300; i += 256) {
        int p = i / 12, k = i - p*12;
        float acc = b0[k];
        #pragma unroll
        for (int m4 = 0; m4 < 7; ++m4) acc += dot4(ldf4(&A0[p*28 + 4*m4]), ldf4(&P0T[k*28 + 4*m4]));
        S0[p*20 + k] = acc;
    }
    __syncthreads();

    if (t < 25) {
        float4 r[3]; float mx = -1e30f;
        #pragma unroll
        for (int u = 0; u < 3; ++u) { r[u] = ldf4(&S0[t*20 + 4*u]); mx = fmaxf(mx, vmax4(r[u])); }
        float sm = 0.f;
        #pragma unroll
        for (int u = 0; u < 3; ++u) { r[u] = exp4(r[u], mx); sm += vsum4(r[u]); }
        float inv = 1.f/sm;
        #pragma unroll
        for (int u = 0; u < 3; ++u) {
            r[u].x *= inv; r[u].y *= inv; r[u].z *= inv; r[u].w *= inv;
            stf4(&S0[t*20 + 4*u], r[u]);
        }
    }
    __syncthreads();

    if (t < 96) {
        int k = t >> 3, c0 = (t & 7) << 3;
        float4 a = {0,0,0,0}, bb = {0,0,0,0};
        #pragma unroll
        for (int p = 0; p < 25; ++p) {
            float s = S0[p*20 + k];
            a  = fma4(s, ldf4(&x0[p*68 + c0]), a);
            bb = fma4(s, ldf4(&x0[p*68 + c0 + 4]), bb);
        }
        stf4(&x1[k*68 + c0], a);
        stf4(&x1[k*68 + c0 + 4], bb);
    }
    __syncthreads();

    if (t < 48) {
        int which = t / 12, p = t - which*12;
        const float* w = wvg + (2+which)*64;
        float a = 0.f;
        #pragma unroll
        for (int c4 = 0; c4 < 16; ++c4) a += dot4(ldf4(&x1[p*68 + 4*c4]), ldf4(&w[4*c4]));
        if (which == 0) sv[p] = a; else if (which == 1) tv[p] = a;
        else if (which == 2) ua[p] = a; else va[p] = a;
    }
    for (int i = t; i < 60; i += 256) {
        int j = i / 12, k = i - j*12;
        float a = 0.f;
        #pragma unroll
        for (int c4 = 0; c4 < 16; ++c4) a += dot4(ldf4(&WpT1[j*64 + 4*c4]), ldf4(&x1[k*68 + 4*c4]));
        P1T[j*12 + k] = a;
    }
    __syncthreads();

    // A1, A1T
    for (int i = t; i < 288; i += 256) {
        int mat = i / 144, rr = (i - mat*144) / 12, q = i % 12;
        if (mat == 0) A1 [rr*20 + q] = lrelu(sv[rr] + tv[q]);
        else          A1T[rr*20 + q] = lrelu(sv[q] + tv[rr]);
    }
    __syncthreads();

    // G1: S1raw = A1@P1 + b1
    for (int i = t; i < 60; i += 256) {
        int m = i / 5, j = i - m*5;
        float acc = b1[j];
        #pragma unroll
        for (int k4 = 0; k4 < 3; ++k4) acc += dot4(ldf4(&A1[m*20 + 4*k4]), ldf4(&P1T[j*12 + 4*k4]));
        S1[m*12 + j] = acc;
    }
    __syncthreads();

    // G2: softmax S1 rows
    if (t < 12) {
        float mx = -1e30f;
        float r0 = S1[t*12+0], r1 = S1[t*12+1], r2 = S1[t*12+2], r3 = S1[t*12+3], r4 = S1[t*12+4];
        mx = fmaxf(fmaxf(fmaxf(r0,r1), fmaxf(r2,r3)), r4);
        r0 = __expf(r0-mx); r1 = __expf(r1-mx); r2 = __expf(r2-mx); r3 = __expf(r3-mx); r4 = __expf(r4-mx);
        float inv = 1.f/(r0+r1+r2+r3+r4);
        S1[t*12+0] = r0*inv; S1[t*12+1] = r1*inv; S1[t*12+2] = r2*inv; S1[t*12+3] = r3*inv; S1[t*12+4] = r4*inv;
    }
    __syncthreads();

    // G2b: rxa/rsa = S1^T . (u,v)
    if (t < 10) {
        int which = t / 5, k = t - which*5;
        float a = 0.f;
        #pragma unroll
        for (int n = 0; n < 12; ++n) a += S1[n*12 + k] * (which ? va[n] : ua[n]);
        if (which) rsa[k] = a; else rxa[k] = a;
    }
    __syncthreads();

    // G3: T1 = S1 @ A2 (A2 = lrelu(rxa + rsa^T) on the fly)  [12][5]
    if (t < 60) {
        int m = t / 5, k = t - m*5;
        float rsk = rsa[k];
        float acc = 0.f;
        #pragma unroll
        for (int j = 0; j < 5; ++j) acc += S1[m*12 + j] * lrelu(rxa[j] + rsk);
        T1[m*5 + k] = acc;
    }
    __syncthreads();

    // G4: B = A1 + T1@S1^T (in place); BT into A1T
    if (t < 144) {
        int m = t / 12, n = t - m*12;
        float acc = A1[m*20 + n];
        #pragma unroll
        for (int j = 0; j < 5; ++j) acc += T1[m*5 + j] * S1[n*12 + j];
        A1[m*20 + n] = acc;
        A1T[n*20 + m] = acc;
    }
    __syncthreads();

    // G5: M1 = S0 @ B (row-dot with BT in A1T)
    for (int i = t; i < 300; i += 256) {
        int p = i / 12, k = i - p*12;
        float acc = 0.f;
        #pragma unroll
        for (int m4 = 0; m4 < 3; ++m4) acc += dot4(ldf4(&S0[p*20 + 4*m4]), ldf4(&A1T[k*20 + 4*m4]));
        M1[p*20 + k] = acc;
    }
    __syncthreads();

    // G6: fusion = A0 + M1@S0^T
    for (int i = t; i < 625; i += 256) {
        int p = i / 25, q = i - p*25;
        float acc = A0[p*28 + q];
        #pragma unroll
        for (int m4 = 0; m4 < 3; ++m4) acc += dot4(ldf4(&M1[p*20 + 4*m4]), ldf4(&S0[q*20 + 4*m4]));
        A0[p*28 + q] = acc;
    }
    __syncthreads();

    // stats
    if (t < 25) {
        float4 r[7]; float mx = -1e30f;
        #pragma unroll
        for (int u = 0; u < 7; ++u) { r[u] = ldf4(&A0[t*28 + 4*u]); mx = fmaxf(mx, vmax4(r[u])); }
        float sm = 0.f;
        #pragma unroll
        for (int u = 0; u < 7; ++u) sm += vsum4(exp4(r[u], mx));
        sv[t] = mx; tv[t] = 1.f/sm;
    }
    __syncthreads();

    for (int i = t; i < 625; i += 256) {
        int p = i / 25, q = i - p*25;
        out[(size_t)g*625 + i] = __expf(A0[p*28 + q] - sv[p]) * tv[p];
    }
}

extern "C" void kernel_launch(void* const* d_in, const int* in_sizes, int n_in,
                              void* d_out, int out_size, void* d_ws, size_t ws_size,
                              hipStream_t stream) {
    const float* src = (const float*)d_in[0];
    const float* W   = (const float*)d_in[1];
    float* ws = (float*)d_ws;

    prep_kernel<<<16, 64, 0, stream>>>(W,
        (const float*)d_in[2],  (const float*)d_in[3],
        (const float*)d_in[6],  (const float*)d_in[7],
        (const float*)d_in[10], (const float*)d_in[11],
        (const float*)d_in[4],  (const float*)d_in[5],
        (const float*)d_in[8],  (const float*)d_in[9],
        (const float*)d_in[12], (const float*)d_in[13],
        (const float*)d_in[14], (const float*)d_in[16],
        (const float*)d_in[18], (const float*)d_in[20],
        ws);

    float* out = (float*)d_out;
    spatial_kernel<<<16384, 256, 0, stream>>>(
        src, ws, ws + 768, ws + 1536,
        (const float*)d_in[15], (const float*)d_in[17],
        out, 16384/8);
    temporal_kernel<<<6400, 512, 0, stream>>>(
        src, ws + 384,
        (const float*)d_in[18], (const float*)d_in[19],
        (const float*)d_in[20], (const float*)d_in[21],
        out + 10240000, 6400/8);
}